// Round 1
// baseline (5512.600 us; speedup 1.0000x reference)
//
#include <hip/hip_runtime.h>
#include <math.h>

#define BB 8
#define CC 192
#define HH 64
#define WW 64
#define LL 4096   // HH*WW
#define DD 192
#define NN 4
#define RR 12
#define KK 4

// ---------------- LayerNorm over channel axis (channels-first) ----------------
// one thread per pixel (b,m); loops over C twice (sum/sumsq then write)
__global__ void ln_cf_kernel(const float* __restrict__ x, const float* __restrict__ w,
                             const float* __restrict__ bias, float* __restrict__ out) {
    int p = blockIdx.x * blockDim.x + threadIdx.x;
    if (p >= BB * LL) return;
    int b = p / LL, m = p % LL;
    const float* xb = x + (size_t)b * CC * LL + m;
    float s = 0.f, s2 = 0.f;
    for (int c = 0; c < CC; c++) { float v = xb[(size_t)c * LL]; s += v; s2 += v * v; }
    float mu = s / CC;
    float var = s2 / CC - mu * mu;
    float r = rsqrtf(var + 1e-5f);
    float* ob = out + (size_t)b * CC * LL + m;
    for (int c = 0; c < CC; c++) {
        float v = xb[(size_t)c * LL];
        ob[(size_t)c * LL] = (v - mu) * r * w[c] + bias[c];
    }
}

// ---------------- in_proj: xz[b,dd,l] = sum_c W[dd,c] * xn[b,c,l] ----------------
// grid (LL/64, 384/32, BB), block (64,4); each thread computes 8 dd outputs for one l
__global__ void in_proj_kernel(const float* __restrict__ xn, const float* __restrict__ wproj,
                               float* __restrict__ xc, float* __restrict__ z) {
    __shared__ float wt[32][CC];  // 24 KB
    int l = blockIdx.x * 64 + threadIdx.x;
    int b = blockIdx.z;
    int dd0 = blockIdx.y * 32;
    int t = threadIdx.y * 64 + threadIdx.x;
    for (int i = t; i < 32 * CC; i += 256)
        wt[i / CC][i % CC] = wproj[(size_t)(dd0 + i / CC) * CC + (i % CC)];
    __syncthreads();
    const float* xb = xn + (size_t)b * CC * LL + l;
    float acc[8];
#pragma unroll
    for (int i = 0; i < 8; i++) acc[i] = 0.f;
    int dl0 = threadIdx.y * 8;
    for (int c = 0; c < CC; c++) {
        float xv = xb[(size_t)c * LL];
#pragma unroll
        for (int i = 0; i < 8; i++) acc[i] = fmaf(wt[dl0 + i][c], xv, acc[i]);
    }
#pragma unroll
    for (int i = 0; i < 8; i++) {
        int dd = dd0 + dl0 + i;
        if (dd < DD) xc[((size_t)b * DD + dd) * LL + l] = acc[i];
        else         z[((size_t)b * DD + (dd - DD)) * LL + l] = acc[i];
    }
}

// ---------------- depthwise 3x3 conv (cross-correlation, SAME) + bias + SiLU ----------------
__global__ void dwconv_silu_kernel(const float* __restrict__ xc, const float* __restrict__ cw,
                                   const float* __restrict__ cb, float* __restrict__ out) {
    int idx = blockIdx.x * blockDim.x + threadIdx.x;
    if (idx >= BB * DD * LL) return;
    int m = idx % LL;
    int bd = idx / LL;
    int d = bd % DD;
    int h = m >> 6, w = m & 63;
    const float* xb = xc + (size_t)bd * LL;
    float acc = cb[d];
#pragma unroll
    for (int i = 0; i < 3; i++) {
        int hh = h + i - 1;
        if (hh < 0 || hh >= HH) continue;
#pragma unroll
        for (int j = 0; j < 3; j++) {
            int ww2 = w + j - 1;
            if (ww2 < 0 || ww2 >= WW) continue;
            acc = fmaf(cw[d * 9 + i * 3 + j], xb[hh * WW + ww2], acc);
        }
    }
    out[idx] = acc / (1.f + expf(-acc));  // SiLU
}

// ---------------- x_proj: for each pixel m, each k: 20 dots of length D ----------------
// stored spatially indexed: dts (B,K,R,L), Bv (B,K,N,L), Cv (B,K,N,L)
// grid ((LL/64)*BB, 20), block (64,4): co = by*4+ty in [0,80)
__global__ void xproj_kernel(const float* __restrict__ xconv, const float* __restrict__ xpw,
                             float* __restrict__ dts, float* __restrict__ Bv,
                             float* __restrict__ Cv) {
    int l = (blockIdx.x % (LL / 64)) * 64 + threadIdx.x;
    int b = blockIdx.x / (LL / 64);
    int co = blockIdx.y * blockDim.y + threadIdx.y;  // 0..79
    int k = co / 20, c = co % 20;
    const float* xb = xconv + (size_t)b * DD * LL + l;
    const float* wrow = xpw + ((size_t)k * 20 + c) * DD;
    float acc = 0.f;
    for (int d = 0; d < DD; d++) acc = fmaf(wrow[d], xb[(size_t)d * LL], acc);
    size_t bk = (size_t)b * KK + k;
    if (c < RR)            dts[(bk * RR + c) * LL + l] = acc;
    else if (c < RR + NN)  Bv[(bk * NN + (c - RR)) * LL + l] = acc;
    else                   Cv[(bk * NN + (c - RR - NN)) * LL + l] = acc;
}

// ---------------- selective scan: one thread per (b,k,d), sequential over L ----------------
// scan-order position t of direction k maps to spatial index m; input u and merged
// output y both live at m, so we read/accumulate in spatial layout directly.
__global__ void scan_kernel(const float* __restrict__ xconv, const float* __restrict__ dts,
                            const float* __restrict__ Bv, const float* __restrict__ Cv,
                            const float* __restrict__ dtw, const float* __restrict__ dtb,
                            const float* __restrict__ A_log, const float* __restrict__ Ds,
                            float* __restrict__ ym) {
    int idx = blockIdx.x * blockDim.x + threadIdx.x;
    if (idx >= BB * KK * DD) return;
    int d = idx % DD;
    int bk = idx / DD;
    int k = bk % KK;
    int b = bk / KK;

    float wrow[RR];
#pragma unroll
    for (int r = 0; r < RR; r++) wrow[r] = dtw[((size_t)k * DD + d) * RR + r];
    float bias = dtb[k * DD + d];
    float Av[NN];
#pragma unroll
    for (int n = 0; n < NN; n++) Av[n] = -expf(A_log[((size_t)k * DD + d) * NN + n]);
    float Dval = Ds[k * DD + d];

    const float* dtsb = dts + (size_t)bk * RR * LL;
    const float* Bb = Bv + (size_t)bk * NN * LL;
    const float* Cb = Cv + (size_t)bk * NN * LL;
    const float* ub = xconv + ((size_t)b * DD + d) * LL;
    float* yb = ym + ((size_t)b * DD + d) * LL;

    float h[NN] = {0.f, 0.f, 0.f, 0.f};
    for (int t = 0; t < LL; t++) {
        int base = (k & 2) ? (LL - 1 - t) : t;
        int m = (k & 1) ? ((base & 63) * 64 + (base >> 6)) : base;
        float u = ub[m];
        float acc = bias;
#pragma unroll
        for (int r = 0; r < RR; r++) acc = fmaf(wrow[r], dtsb[(size_t)r * LL + m], acc);
        float dt = (acc > 20.f) ? acc : log1pf(expf(acc));
        float y = Dval * u;
#pragma unroll
        for (int n = 0; n < NN; n++) {
            float bn = Bb[(size_t)n * LL + m];
            float cn = Cb[(size_t)n * LL + m];
            float dA = expf(dt * Av[n]);
            h[n] = dA * h[n] + dt * bn * u;
            y = fmaf(h[n], cn, y);
        }
        atomicAdd(&yb[m], y);
    }
}

// ---------------- merge-LN over D + gate with silu(z), in place on ym ----------------
__global__ void lngate_kernel(float* __restrict__ ym, const float* __restrict__ z,
                              const float* __restrict__ wn, const float* __restrict__ bn) {
    int p = blockIdx.x * blockDim.x + threadIdx.x;
    if (p >= BB * LL) return;
    int b = p / LL, m = p % LL;
    float* yb = ym + (size_t)b * DD * LL + m;
    const float* zb = z + (size_t)b * DD * LL + m;
    float s = 0.f, s2 = 0.f;
    for (int d = 0; d < DD; d++) { float v = yb[(size_t)d * LL]; s += v; s2 += v * v; }
    float mu = s / DD;
    float var = s2 / DD - mu * mu;
    float r = rsqrtf(var + 1e-5f);
    for (int d = 0; d < DD; d++) {
        float v = yb[(size_t)d * LL];
        float zv = zb[(size_t)d * LL];
        float g = zv / (1.f + expf(-zv));
        yb[(size_t)d * LL] = ((v - mu) * r * wn[d] + bn[d]) * g;
    }
}

// ---------------- out_proj + residual ----------------
// grid (LL/64, CC/32, BB), block (64,4)
__global__ void out_proj_kernel(const float* __restrict__ yg, const float* __restrict__ wproj,
                                const float* __restrict__ x, float* __restrict__ out) {
    __shared__ float wt[32][DD];
    int l = blockIdx.x * 64 + threadIdx.x;
    int b = blockIdx.z;
    int c0 = blockIdx.y * 32;
    int t = threadIdx.y * 64 + threadIdx.x;
    for (int i = t; i < 32 * DD; i += 256)
        wt[i / DD][i % DD] = wproj[(size_t)(c0 + i / DD) * DD + (i % DD)];
    __syncthreads();
    const float* yb = yg + (size_t)b * DD * LL + l;
    float acc[8];
#pragma unroll
    for (int i = 0; i < 8; i++) acc[i] = 0.f;
    int cl0 = threadIdx.y * 8;
    for (int d = 0; d < DD; d++) {
        float yv = yb[(size_t)d * LL];
#pragma unroll
        for (int i = 0; i < 8; i++) acc[i] = fmaf(wt[cl0 + i][d], yv, acc[i]);
    }
#pragma unroll
    for (int i = 0; i < 8; i++) {
        int c = c0 + cl0 + i;
        size_t o = ((size_t)b * CC + c) * LL + l;
        out[o] = acc[i] + x[o];
    }
}

extern "C" void kernel_launch(void* const* d_in, const int* in_sizes, int n_in,
                              void* d_out, int out_size, void* d_ws, size_t ws_size,
                              hipStream_t stream) {
    const float* x          = (const float*)d_in[0];
    const float* ln_w       = (const float*)d_in[1];
    const float* ln_b       = (const float*)d_in[2];
    const float* in_proj_w  = (const float*)d_in[3];
    const float* conv_w     = (const float*)d_in[4];
    const float* conv_b     = (const float*)d_in[5];
    const float* x_proj_w   = (const float*)d_in[6];
    const float* dt_proj_w  = (const float*)d_in[7];
    const float* dt_proj_b  = (const float*)d_in[8];
    const float* A_log      = (const float*)d_in[9];
    const float* Ds         = (const float*)d_in[10];
    const float* out_norm_w = (const float*)d_in[11];
    const float* out_norm_b = (const float*)d_in[12];
    const float* out_proj_w = (const float*)d_in[13];
    float* out = (float*)d_out;

    const size_t P = (size_t)BB * CC * LL;  // 6,291,456 elements
    float* ws = (float*)d_ws;
    // buffer reuse: buf0 = xn then ym; buf1 = xc then {dts,Bv,Cv}; buf2 = z; buf3 = xconv
    float* xn    = ws;            // P
    float* xc    = ws + P;        // P
    float* z     = ws + 2 * P;    // P
    float* xconv = ws + 3 * P;    // P
    float* ym    = xn;            // reuse after in_proj consumed xn
    float* dts   = xc;            // reuse after conv consumed xc: B*K*R*L = 1,572,864
    float* Bv    = dts + (size_t)BB * KK * RR * LL;  // 524,288
    float* Cv    = Bv + (size_t)BB * KK * NN * LL;   // 524,288  (total 2.62M < P)

    // 1. LayerNorm (channels-first)
    ln_cf_kernel<<<(BB * LL) / 256, 256, 0, stream>>>(x, ln_w, ln_b, xn);
    // 2. in_proj -> xc, z
    in_proj_kernel<<<dim3(LL / 64, (2 * DD) / 32, BB), dim3(64, 4), 0, stream>>>(
        xn, in_proj_w, xc, z);
    // ym reuses xn's buffer; zero it now (xn no longer needed)
    hipMemsetAsync(ym, 0, P * sizeof(float), stream);
    // 3. depthwise conv + SiLU
    dwconv_silu_kernel<<<(BB * DD * LL) / 256, 256, 0, stream>>>(xc, conv_w, conv_b, xconv);
    // 4. x_proj (spatially indexed dts/Bv/Cv)
    xproj_kernel<<<dim3((LL / 64) * BB, 20), dim3(64, 4), 0, stream>>>(
        xconv, x_proj_w, dts, Bv, Cv);
    // 5. selective scan, 4 directions, accumulate merged y
    scan_kernel<<<(BB * KK * DD + 255) / 256, 256, 0, stream>>>(
        xconv, dts, Bv, Cv, dt_proj_w, dt_proj_b, A_log, Ds, ym);
    // 6. LN over D + silu(z) gate, in place
    lngate_kernel<<<(BB * LL) / 256, 256, 0, stream>>>(ym, z, out_norm_w, out_norm_b);
    // 7. out_proj + residual
    out_proj_kernel<<<dim3(LL / 64, CC / 32, BB), dim3(64, 4), 0, stream>>>(
        ym, out_proj_w, x, out);
}

// Round 2
// 1931.000 us; speedup vs baseline: 2.8548x; 2.8548x over previous
//
#include <hip/hip_runtime.h>
#include <math.h>

#define BB 8
#define CC 192
#define HH 64
#define WW 64
#define LL 4096   // HH*WW
#define DD 192
#define NN 4
#define RR 12
#define KK 4
#define CH 32     // chunks per direction
#define SS 128    // chunk length (CH*SS == LL)

// ---------------- LayerNorm over channel axis (channels-first) ----------------
__global__ void ln_cf_kernel(const float* __restrict__ x, const float* __restrict__ w,
                             const float* __restrict__ bias, float* __restrict__ out) {
    int p = blockIdx.x * blockDim.x + threadIdx.x;
    if (p >= BB * LL) return;
    int b = p / LL, m = p % LL;
    const float* xb = x + (size_t)b * CC * LL + m;
    float s = 0.f, s2 = 0.f;
    for (int c = 0; c < CC; c++) { float v = xb[(size_t)c * LL]; s += v; s2 += v * v; }
    float mu = s / CC;
    float var = s2 / CC - mu * mu;
    float r = rsqrtf(var + 1e-5f);
    float* ob = out + (size_t)b * CC * LL + m;
    for (int c = 0; c < CC; c++) {
        float v = xb[(size_t)c * LL];
        ob[(size_t)c * LL] = (v - mu) * r * w[c] + bias[c];
    }
}

// ---------------- in_proj ----------------
__global__ void in_proj_kernel(const float* __restrict__ xn, const float* __restrict__ wproj,
                               float* __restrict__ xc, float* __restrict__ z) {
    __shared__ float wt[32][CC];  // 24 KB
    int l = blockIdx.x * 64 + threadIdx.x;
    int b = blockIdx.z;
    int dd0 = blockIdx.y * 32;
    int t = threadIdx.y * 64 + threadIdx.x;
    for (int i = t; i < 32 * CC; i += 256)
        wt[i / CC][i % CC] = wproj[(size_t)(dd0 + i / CC) * CC + (i % CC)];
    __syncthreads();
    const float* xb = xn + (size_t)b * CC * LL + l;
    float acc[8];
#pragma unroll
    for (int i = 0; i < 8; i++) acc[i] = 0.f;
    int dl0 = threadIdx.y * 8;
    for (int c = 0; c < CC; c++) {
        float xv = xb[(size_t)c * LL];
#pragma unroll
        for (int i = 0; i < 8; i++) acc[i] = fmaf(wt[dl0 + i][c], xv, acc[i]);
    }
#pragma unroll
    for (int i = 0; i < 8; i++) {
        int dd = dd0 + dl0 + i;
        if (dd < DD) xc[((size_t)b * DD + dd) * LL + l] = acc[i];
        else         z[((size_t)b * DD + (dd - DD)) * LL + l] = acc[i];
    }
}

// ---------------- depthwise 3x3 conv + bias + SiLU ----------------
__global__ void dwconv_silu_kernel(const float* __restrict__ xc, const float* __restrict__ cw,
                                   const float* __restrict__ cb, float* __restrict__ out) {
    int idx = blockIdx.x * blockDim.x + threadIdx.x;
    if (idx >= BB * DD * LL) return;
    int m = idx % LL;
    int bd = idx / LL;
    int d = bd % DD;
    int h = m >> 6, w = m & 63;
    const float* xb = xc + (size_t)bd * LL;
    float acc = cb[d];
#pragma unroll
    for (int i = 0; i < 3; i++) {
        int hh = h + i - 1;
        if (hh < 0 || hh >= HH) continue;
#pragma unroll
        for (int j = 0; j < 3; j++) {
            int ww2 = w + j - 1;
            if (ww2 < 0 || ww2 >= WW) continue;
            acc = fmaf(cw[d * 9 + i * 3 + j], xb[hh * WW + ww2], acc);
        }
    }
    out[idx] = acc / (1.f + expf(-acc));  // SiLU
}

// ---------------- x_proj ----------------
__global__ void xproj_kernel(const float* __restrict__ xconv, const float* __restrict__ xpw,
                             float* __restrict__ dts, float* __restrict__ Bv,
                             float* __restrict__ Cv) {
    int l = (blockIdx.x % (LL / 64)) * 64 + threadIdx.x;
    int b = blockIdx.x / (LL / 64);
    int co = blockIdx.y * blockDim.y + threadIdx.y;  // 0..79
    int k = co / 20, c = co % 20;
    const float* xb = xconv + (size_t)b * DD * LL + l;
    const float* wrow = xpw + ((size_t)k * 20 + c) * DD;
    float acc = 0.f;
    for (int d = 0; d < DD; d++) acc = fmaf(wrow[d], xb[(size_t)d * LL], acc);
    size_t bk = (size_t)b * KK + k;
    if (c < RR)            dts[(bk * RR + c) * LL + l] = acc;
    else if (c < RR + NN)  Bv[(bk * NN + (c - RR)) * LL + l] = acc;
    else                   Cv[(bk * NN + (c - RR - NN)) * LL + l] = acc;
}

// ---------------- scan part1: per-chunk local scan (h0 = 0) ----------------
__global__ void scan_part1(const float* __restrict__ xconv, const float* __restrict__ dts,
                           const float* __restrict__ Bv,
                           const float* __restrict__ dtw, const float* __restrict__ dtb,
                           const float* __restrict__ A_log, float* __restrict__ chunkstate) {
    int blk = blockIdx.x;
    int c = blk % CH;
    int bk = blk / CH;
    int k = bk % KK, b = bk / KK;
    int d = threadIdx.x;

    float wrow[RR];
#pragma unroll
    for (int r = 0; r < RR; r++) wrow[r] = dtw[((size_t)k * DD + d) * RR + r];
    float bias = dtb[k * DD + d];
    float Av[NN];
#pragma unroll
    for (int n = 0; n < NN; n++) Av[n] = -expf(A_log[((size_t)k * DD + d) * NN + n]);

    const float* dtsb = dts + (size_t)bk * RR * LL;
    const float* Bb = Bv + (size_t)bk * NN * LL;
    const float* ub = xconv + ((size_t)b * DD + d) * LL;

    float Ap[NN] = {1.f, 1.f, 1.f, 1.f};
    float h[NN] = {0.f, 0.f, 0.f, 0.f};
    for (int t = 0; t < SS; t++) {
        int g = c * SS + t;
        int base = (k & 2) ? (LL - 1 - g) : g;
        int m = (k & 1) ? ((base & 63) * 64 + (base >> 6)) : base;
        float acc = bias;
#pragma unroll
        for (int r = 0; r < RR; r++) acc = fmaf(wrow[r], dtsb[(size_t)r * LL + m], acc);
        float dt = (acc > 20.f) ? acc : log1pf(expf(acc));
        float u = ub[m];
        float dtu = dt * u;
#pragma unroll
        for (int n = 0; n < NN; n++) {
            float a = expf(dt * Av[n]);
            Ap[n] *= a;
            h[n] = fmaf(a, h[n], dtu * Bb[(size_t)n * LL + m]);
        }
    }
    float* cs = chunkstate + (((size_t)bk * CH + c) * DD + d) * 8;
#pragma unroll
    for (int n = 0; n < NN; n++) { cs[n] = Ap[n]; cs[4 + n] = h[n]; }
}

// ---------------- scan part2: sequential combine over chunks; emit hinit ----------------
__global__ void scan_part2(const float* __restrict__ chunkstate, float* __restrict__ hinit) {
    int idx = blockIdx.x * blockDim.x + threadIdx.x;
    if (idx >= BB * KK * DD) return;
    int d = idx % DD;
    int bk = idx / DD;
    float h[NN] = {0.f, 0.f, 0.f, 0.f};
    for (int c = 0; c < CH; c++) {
        size_t base = (((size_t)bk * CH + c) * DD + d);
        const float* cs = chunkstate + base * 8;
        float* hi = hinit + base * 4;
#pragma unroll
        for (int n = 0; n < NN; n++) hi[n] = h[n];
#pragma unroll
        for (int n = 0; n < NN; n++) h[n] = fmaf(cs[n], h[n], cs[4 + n]);
    }
}

// ---------------- scan part3: re-run chunk from hinit, emit y (atomicAdd merge) ----------------
__global__ void scan_part3(const float* __restrict__ xconv, const float* __restrict__ dts,
                           const float* __restrict__ Bv, const float* __restrict__ Cv,
                           const float* __restrict__ dtw, const float* __restrict__ dtb,
                           const float* __restrict__ A_log, const float* __restrict__ Ds,
                           const float* __restrict__ hinit, float* __restrict__ ym) {
    int blk = blockIdx.x;
    int c = blk % CH;
    int bk = blk / CH;
    int k = bk % KK, b = bk / KK;
    int d = threadIdx.x;

    float wrow[RR];
#pragma unroll
    for (int r = 0; r < RR; r++) wrow[r] = dtw[((size_t)k * DD + d) * RR + r];
    float bias = dtb[k * DD + d];
    float Av[NN];
#pragma unroll
    for (int n = 0; n < NN; n++) Av[n] = -expf(A_log[((size_t)k * DD + d) * NN + n]);
    float Dval = Ds[k * DD + d];

    const float* dtsb = dts + (size_t)bk * RR * LL;
    const float* Bb = Bv + (size_t)bk * NN * LL;
    const float* Cb = Cv + (size_t)bk * NN * LL;
    const float* ub = xconv + ((size_t)b * DD + d) * LL;
    float* yb = ym + ((size_t)b * DD + d) * LL;

    float h[NN];
    const float* hi = hinit + (((size_t)bk * CH + c) * DD + d) * 4;
#pragma unroll
    for (int n = 0; n < NN; n++) h[n] = hi[n];

    for (int t = 0; t < SS; t++) {
        int g = c * SS + t;
        int base = (k & 2) ? (LL - 1 - g) : g;
        int m = (k & 1) ? ((base & 63) * 64 + (base >> 6)) : base;
        float acc = bias;
#pragma unroll
        for (int r = 0; r < RR; r++) acc = fmaf(wrow[r], dtsb[(size_t)r * LL + m], acc);
        float dt = (acc > 20.f) ? acc : log1pf(expf(acc));
        float u = ub[m];
        float dtu = dt * u;
        float y = Dval * u;
#pragma unroll
        for (int n = 0; n < NN; n++) {
            float a = expf(dt * Av[n]);
            h[n] = fmaf(a, h[n], dtu * Bb[(size_t)n * LL + m]);
            y = fmaf(h[n], Cb[(size_t)n * LL + m], y);
        }
        atomicAdd(&yb[m], y);
    }
}

// ---------------- merge-LN over D + gate with silu(z) ----------------
__global__ void lngate_kernel(float* __restrict__ ym, const float* __restrict__ z,
                              const float* __restrict__ wn, const float* __restrict__ bn) {
    int p = blockIdx.x * blockDim.x + threadIdx.x;
    if (p >= BB * LL) return;
    int b = p / LL, m = p % LL;
    float* yb = ym + (size_t)b * DD * LL + m;
    const float* zb = z + (size_t)b * DD * LL + m;
    float s = 0.f, s2 = 0.f;
    for (int d = 0; d < DD; d++) { float v = yb[(size_t)d * LL]; s += v; s2 += v * v; }
    float mu = s / DD;
    float var = s2 / DD - mu * mu;
    float r = rsqrtf(var + 1e-5f);
    for (int d = 0; d < DD; d++) {
        float v = yb[(size_t)d * LL];
        float zv = zb[(size_t)d * LL];
        float g = zv / (1.f + expf(-zv));
        yb[(size_t)d * LL] = ((v - mu) * r * wn[d] + bn[d]) * g;
    }
}

// ---------------- out_proj + residual ----------------
__global__ void out_proj_kernel(const float* __restrict__ yg, const float* __restrict__ wproj,
                                const float* __restrict__ x, float* __restrict__ out) {
    __shared__ float wt[32][DD];
    int l = blockIdx.x * 64 + threadIdx.x;
    int b = blockIdx.z;
    int c0 = blockIdx.y * 32;
    int t = threadIdx.y * 64 + threadIdx.x;
    for (int i = t; i < 32 * DD; i += 256)
        wt[i / DD][i % DD] = wproj[(size_t)(c0 + i / DD) * DD + (i % DD)];
    __syncthreads();
    const float* yb = yg + (size_t)b * DD * LL + l;
    float acc[8];
#pragma unroll
    for (int i = 0; i < 8; i++) acc[i] = 0.f;
    int cl0 = threadIdx.y * 8;
    for (int d = 0; d < DD; d++) {
        float yv = yb[(size_t)d * LL];
#pragma unroll
        for (int i = 0; i < 8; i++) acc[i] = fmaf(wt[cl0 + i][d], yv, acc[i]);
    }
#pragma unroll
    for (int i = 0; i < 8; i++) {
        int c = c0 + cl0 + i;
        size_t o = ((size_t)b * CC + c) * LL + l;
        out[o] = acc[i] + x[o];
    }
}

extern "C" void kernel_launch(void* const* d_in, const int* in_sizes, int n_in,
                              void* d_out, int out_size, void* d_ws, size_t ws_size,
                              hipStream_t stream) {
    const float* x          = (const float*)d_in[0];
    const float* ln_w       = (const float*)d_in[1];
    const float* ln_b       = (const float*)d_in[2];
    const float* in_proj_w  = (const float*)d_in[3];
    const float* conv_w     = (const float*)d_in[4];
    const float* conv_b     = (const float*)d_in[5];
    const float* x_proj_w   = (const float*)d_in[6];
    const float* dt_proj_w  = (const float*)d_in[7];
    const float* dt_proj_b  = (const float*)d_in[8];
    const float* A_log      = (const float*)d_in[9];
    const float* Ds         = (const float*)d_in[10];
    const float* out_norm_w = (const float*)d_in[11];
    const float* out_norm_b = (const float*)d_in[12];
    const float* out_proj_w = (const float*)d_in[13];
    float* out = (float*)d_out;

    const size_t P = (size_t)BB * CC * LL;  // 6,291,456 elements
    float* ws = (float*)d_ws;
    // buf0: xn, then ym.  buf1: dts/Bv/Cv + chunkstate + hinit.  buf2: z.  buf3: xconv.
    float* xn    = ws;
    float* buf1  = ws + P;
    float* z     = ws + 2 * P;
    float* xconv = ws + 3 * P;
    float* ym    = xn;
    float* dts = buf1;                                         // 1,572,864
    float* Bv  = dts + (size_t)BB * KK * RR * LL;              //   524,288
    float* Cv  = Bv + (size_t)BB * KK * NN * LL;               //   524,288
    float* chunkstate = Cv + (size_t)BB * KK * NN * LL;        // 1,572,864
    float* hinit = chunkstate + (size_t)BB * KK * CH * DD * 8; //   786,432
    // buf1 total: 4,980,736 <= P ✓

    // 1. LayerNorm
    ln_cf_kernel<<<(BB * LL) / 256, 256, 0, stream>>>(x, ln_w, ln_b, xn);
    // 2. in_proj -> xconv-input (stored temporarily in xconv buffer's slot? no: store to buf3 later)
    //    xc lives in xconv buffer? No: conv reads xc and writes xconv. Use z..? We need two P buffers:
    //    xc -> stored in the buf1 region is too small. Store xc in the xconv buffer, conv writes over... 
    //    conv reads 3x3 neighborhood -> cannot be in-place. Store xc in buf1? (4.98M used later, but
    //    dts/Bv/Cv not yet written). xc needs P > remaining. Solution: xc goes to xconv buffer, conv
    //    output goes to buf1 temporarily? Also too small. Instead: keep xc in ws+3P (xconv slot) and
    //    write conv output into xn (free after in_proj? NO - needed... xn free after in_proj).
    in_proj_kernel<<<dim3(LL / 64, (2 * DD) / 32, BB), dim3(64, 4), 0, stream>>>(
        xn, in_proj_w, xconv /*xc pre-conv*/, z);
    // 3. conv: reads xc (in xconv slot), writes to xn slot (xn consumed). Then xn slot holds xconv-final?
    //    But ym also wants xn slot. Swap roles: conv output -> xn slot is "xconv_final"; ym -> xconv slot.
    dwconv_silu_kernel<<<(BB * DD * LL) / 256, 256, 0, stream>>>(xconv, conv_w, conv_b, xn);
    // From here: xn slot = xconv_final (call it xcv), xconv slot = free -> ym.
    float* xcv = xn;
    float* ym2 = xconv;
    hipMemsetAsync(ym2, 0, P * sizeof(float), stream);
    // 4. x_proj
    xproj_kernel<<<dim3((LL / 64) * BB, 20), dim3(64, 4), 0, stream>>>(
        xcv, x_proj_w, dts, Bv, Cv);
    // 5. scan
    scan_part1<<<BB * KK * CH, DD, 0, stream>>>(xcv, dts, Bv, dt_proj_w, dt_proj_b,
                                                A_log, chunkstate);
    scan_part2<<<(BB * KK * DD + 255) / 256, 256, 0, stream>>>(chunkstate, hinit);
    scan_part3<<<BB * KK * CH, DD, 0, stream>>>(xcv, dts, Bv, Cv, dt_proj_w, dt_proj_b,
                                                A_log, Ds, hinit, ym2);
    // 6. LN over D + gate
    lngate_kernel<<<(BB * LL) / 256, 256, 0, stream>>>(ym2, z, out_norm_w, out_norm_b);
    // 7. out_proj + residual
    out_proj_kernel<<<dim3(LL / 64, CC / 32, BB), dim3(64, 4), 0, stream>>>(
        ym2, out_proj_w, x, out);
}

// Round 3
// 623.424 us; speedup vs baseline: 8.8425x; 3.0974x over previous
//
#include <hip/hip_runtime.h>
#include <math.h>

#define BB 8
#define CC 192
#define HH 64
#define WW 64
#define LL 4096   // HH*WW
#define DD 192
#define NN 4
#define RR 12
#define KK 4
#define CH 32     // chunks per direction
#define SS 128    // chunk length (CH*SS == LL)

// ---------------- LayerNorm over channel axis (channels-first) ----------------
__global__ void ln_cf_kernel(const float* __restrict__ x, const float* __restrict__ w,
                             const float* __restrict__ bias, float* __restrict__ out) {
    int p = blockIdx.x * blockDim.x + threadIdx.x;
    if (p >= BB * LL) return;
    int b = p / LL, m = p % LL;
    const float* xb = x + (size_t)b * CC * LL + m;
    float s = 0.f, s2 = 0.f;
    for (int c = 0; c < CC; c++) { float v = xb[(size_t)c * LL]; s += v; s2 += v * v; }
    float mu = s / CC;
    float var = s2 / CC - mu * mu;
    float r = rsqrtf(var + 1e-5f);
    float* ob = out + (size_t)b * CC * LL + m;
    for (int c = 0; c < CC; c++) {
        float v = xb[(size_t)c * LL];
        ob[(size_t)c * LL] = (v - mu) * r * w[c] + bias[c];
    }
}

// ---------------- in_proj (channel-major in/out) ----------------
__global__ void in_proj_kernel(const float* __restrict__ xn, const float* __restrict__ wproj,
                               float* __restrict__ xc, float* __restrict__ z) {
    __shared__ float wt[32][CC];  // 24 KB
    int l = blockIdx.x * 64 + threadIdx.x;
    int b = blockIdx.z;
    int dd0 = blockIdx.y * 32;
    int t = threadIdx.y * 64 + threadIdx.x;
    for (int i = t; i < 32 * CC; i += 256)
        wt[i / CC][i % CC] = wproj[(size_t)(dd0 + i / CC) * CC + (i % CC)];
    __syncthreads();
    const float* xb = xn + (size_t)b * CC * LL + l;
    float acc[8];
#pragma unroll
    for (int i = 0; i < 8; i++) acc[i] = 0.f;
    int dl0 = threadIdx.y * 8;
    for (int c = 0; c < CC; c++) {
        float xv = xb[(size_t)c * LL];
#pragma unroll
        for (int i = 0; i < 8; i++) acc[i] = fmaf(wt[dl0 + i][c], xv, acc[i]);
    }
#pragma unroll
    for (int i = 0; i < 8; i++) {
        int dd = dd0 + dl0 + i;
        if (dd < DD) xc[((size_t)b * DD + dd) * LL + l] = acc[i];
        else         z[((size_t)b * DD + (dd - DD)) * LL + l] = acc[i];
    }
}

// ---------------- depthwise 3x3 conv + bias + SiLU (channel-major) ----------------
__global__ void dwconv_silu_kernel(const float* __restrict__ xc, const float* __restrict__ cw,
                                   const float* __restrict__ cb, float* __restrict__ out) {
    int idx = blockIdx.x * blockDim.x + threadIdx.x;
    if (idx >= BB * DD * LL) return;
    int m = idx % LL;
    int bd = idx / LL;
    int d = bd % DD;
    int h = m >> 6, w = m & 63;
    const float* xb = xc + (size_t)bd * LL;
    float acc = cb[d];
#pragma unroll
    for (int i = 0; i < 3; i++) {
        int hh = h + i - 1;
        if (hh < 0 || hh >= HH) continue;
#pragma unroll
        for (int j = 0; j < 3; j++) {
            int ww2 = w + j - 1;
            if (ww2 < 0 || ww2 >= WW) continue;
            acc = fmaf(cw[d * 9 + i * 3 + j], xb[hh * WW + ww2], acc);
        }
    }
    out[idx] = acc / (1.f + __expf(-acc));  // SiLU
}

// ---------------- transpose (b, d, L) -> (b, L, d) pixel-major ----------------
__global__ void transpose_kernel(const float* __restrict__ in, float* __restrict__ out) {
    __shared__ float tile[64][65];
    int b = blockIdx.z;
    int d0 = blockIdx.y * 64;   // 0..2
    int m0 = blockIdx.x * 64;   // 0..63
    int tx = threadIdx.x, ty = threadIdx.y;  // (64,4)
#pragma unroll
    for (int j = 0; j < 16; j++) {
        int d = ty + 4 * j;
        tile[d][tx] = in[((size_t)b * DD + d0 + d) * LL + m0 + tx];
    }
    __syncthreads();
#pragma unroll
    for (int j = 0; j < 16; j++) {
        int m = ty + 4 * j;
        out[((size_t)b * LL + m0 + m) * DD + d0 + tx] = tile[tx][m];
    }
}

// ---------------- x_proj: pixel-major input -> interleaved x_dbl (b,k,m,20) ----------------
// block: 64 pixels x 4 waves (wave = one direction k). LDS tile padded to 193.
__global__ void xproj_kernel(const float* __restrict__ xT, const float* __restrict__ xpw,
                             float* __restrict__ xdbl) {
    __shared__ float xt[64 * 193];  // 49.4 KB
    int b = blockIdx.x / (LL / 64);
    int m0 = (blockIdx.x % (LL / 64)) * 64;
    int tx = threadIdx.x, k = threadIdx.y;
    int t = k * 64 + tx;
    const float* src = xT + ((size_t)b * LL + m0) * DD;
    for (int i = t; i < 64 * DD; i += 256) {
        int p = i / DD, d = i % DD;
        xt[p * 193 + d] = src[(size_t)p * DD + d];
    }
    __syncthreads();
    float acc[20];
#pragma unroll
    for (int c = 0; c < 20; c++) acc[c] = 0.f;
    const float* wk = xpw + (size_t)k * 20 * DD;
    for (int d = 0; d < DD; d++) {
        float xv = xt[tx * 193 + d];
#pragma unroll
        for (int c = 0; c < 20; c++) acc[c] = fmaf(wk[c * DD + d], xv, acc[c]);
    }
    float* o = xdbl + (((size_t)(b * KK + k) * LL) + m0 + tx) * 20;
#pragma unroll
    for (int c = 0; c < 20; c++) o[c] = acc[c];
}

// ---------------- scan part1: per-chunk local scan (h0 = 0) ----------------
// block = 192 threads (=d), grid = B*K*CH
__global__ void scan_part1(const float* __restrict__ uT, const float* __restrict__ xdbl,
                           const float* __restrict__ dtw, const float* __restrict__ dtb,
                           const float* __restrict__ A_log, float* __restrict__ cs) {
    int blk = blockIdx.x;
    int cch = blk % CH;
    int bk = blk / CH;
    int k = bk % KK, b = bk / KK;
    int d = threadIdx.x;

    float wrow[RR];
#pragma unroll
    for (int r = 0; r < RR; r++) wrow[r] = dtw[((size_t)k * DD + d) * RR + r];
    float bias = dtb[k * DD + d];
    float Av[NN];
#pragma unroll
    for (int n = 0; n < NN; n++) Av[n] = -__expf(A_log[((size_t)k * DD + d) * NN + n]);

    float Ap[NN] = {1.f, 1.f, 1.f, 1.f};
    float h[NN] = {0.f, 0.f, 0.f, 0.f};
    for (int t = 0; t < SS; t++) {
        int g = cch * SS + t;
        int base = (k & 2) ? (LL - 1 - g) : g;
        int m = (k & 1) ? ((base & 63) * 64 + (base >> 6)) : base;
        const float* xd = xdbl + ((size_t)bk * LL + m) * 20;
        float acc = bias;
#pragma unroll
        for (int r = 0; r < RR; r++) acc = fmaf(wrow[r], xd[r], acc);
        float e = __expf(acc);
        float dt = (acc > 20.f) ? acc : __logf(1.f + e);
        float u = uT[((size_t)b * LL + m) * DD + d];
        float dtu = dt * u;
#pragma unroll
        for (int n = 0; n < NN; n++) {
            float a = __expf(dt * Av[n]);
            Ap[n] *= a;
            h[n] = fmaf(a, h[n], dtu * xd[12 + n]);
        }
    }
    size_t cb = (size_t)bk * CH + cch;
#pragma unroll
    for (int n = 0; n < NN; n++) {
        cs[(cb * 8 + n) * DD + d] = Ap[n];
        cs[(cb * 8 + 4 + n) * DD + d] = h[n];
    }
}

// ---------------- scan part2: sequential combine over chunks; emit hinit ----------------
__global__ void scan_part2(const float* __restrict__ cs, float* __restrict__ hinit) {
    int idx = blockIdx.x * blockDim.x + threadIdx.x;
    if (idx >= BB * KK * DD) return;
    int d = idx % DD;
    int bk = idx / DD;
    float h[NN] = {0.f, 0.f, 0.f, 0.f};
    for (int c = 0; c < CH; c++) {
        size_t cb = (size_t)bk * CH + c;
#pragma unroll
        for (int n = 0; n < NN; n++) hinit[(cb * 4 + n) * DD + d] = h[n];
#pragma unroll
        for (int n = 0; n < NN; n++)
            h[n] = fmaf(cs[(cb * 8 + n) * DD + d], h[n], cs[(cb * 8 + 4 + n) * DD + d]);
    }
}

// ---------------- scan part3: re-run chunk from hinit, atomicAdd merged y ----------------
__global__ void scan_part3(const float* __restrict__ uT, const float* __restrict__ xdbl,
                           const float* __restrict__ dtw, const float* __restrict__ dtb,
                           const float* __restrict__ A_log, const float* __restrict__ Ds,
                           const float* __restrict__ hinit, float* __restrict__ ymT) {
    int blk = blockIdx.x;
    int cch = blk % CH;
    int bk = blk / CH;
    int k = bk % KK, b = bk / KK;
    int d = threadIdx.x;

    float wrow[RR];
#pragma unroll
    for (int r = 0; r < RR; r++) wrow[r] = dtw[((size_t)k * DD + d) * RR + r];
    float bias = dtb[k * DD + d];
    float Av[NN];
#pragma unroll
    for (int n = 0; n < NN; n++) Av[n] = -__expf(A_log[((size_t)k * DD + d) * NN + n]);
    float Dval = Ds[k * DD + d];

    float h[NN];
    size_t cb = (size_t)bk * CH + cch;
#pragma unroll
    for (int n = 0; n < NN; n++) h[n] = hinit[(cb * 4 + n) * DD + d];

    for (int t = 0; t < SS; t++) {
        int g = cch * SS + t;
        int base = (k & 2) ? (LL - 1 - g) : g;
        int m = (k & 1) ? ((base & 63) * 64 + (base >> 6)) : base;
        const float* xd = xdbl + ((size_t)bk * LL + m) * 20;
        float acc = bias;
#pragma unroll
        for (int r = 0; r < RR; r++) acc = fmaf(wrow[r], xd[r], acc);
        float e = __expf(acc);
        float dt = (acc > 20.f) ? acc : __logf(1.f + e);
        float u = uT[((size_t)b * LL + m) * DD + d];
        float dtu = dt * u;
        float y = Dval * u;
#pragma unroll
        for (int n = 0; n < NN; n++) {
            float a = __expf(dt * Av[n]);
            h[n] = fmaf(a, h[n], dtu * xd[12 + n]);
            y = fmaf(h[n], xd[16 + n], y);
        }
        atomicAdd(&ymT[((size_t)b * LL + m) * DD + d], y);
    }
}

// ---------------- merge-LN over D + silu(z) gate; pixel-major ym -> channel-major ygate ----
// block: 64 pixels x 4 waves
__global__ void lngate_kernel(const float* __restrict__ ymT, const float* __restrict__ z,
                              const float* __restrict__ wn, const float* __restrict__ bn,
                              float* __restrict__ yg) {
    __shared__ float yt[64 * 193];   // 49.4 KB
    __shared__ float red[2][4][64];
    __shared__ float stat[2][64];
    int b = blockIdx.x / (LL / 64);
    int m0 = (blockIdx.x % (LL / 64)) * 64;
    int tx = threadIdx.x, ty = threadIdx.y;
    int t = ty * 64 + tx;
    const float* src = ymT + ((size_t)b * LL + m0) * DD;
    for (int i = t; i < 64 * DD; i += 256) {
        int p = i / DD, d = i % DD;
        yt[p * 193 + d] = src[(size_t)p * DD + d];
    }
    __syncthreads();
    float s = 0.f, s2 = 0.f;
    for (int j = 0; j < 48; j++) {
        int d = ty * 48 + j;
        float v = yt[tx * 193 + d];
        s += v; s2 += v * v;
    }
    red[0][ty][tx] = s; red[1][ty][tx] = s2;
    __syncthreads();
    if (ty == 0) {
        float ss = red[0][0][tx] + red[0][1][tx] + red[0][2][tx] + red[0][3][tx];
        float ss2 = red[1][0][tx] + red[1][1][tx] + red[1][2][tx] + red[1][3][tx];
        float mu = ss / DD;
        float var = ss2 / DD - mu * mu;
        stat[0][tx] = mu;
        stat[1][tx] = rsqrtf(var + 1e-5f);
    }
    __syncthreads();
    float mu = stat[0][tx], r = stat[1][tx];
    for (int j = 0; j < 48; j++) {
        int d = ty * 48 + j;
        float v = yt[tx * 193 + d];
        float zv = z[((size_t)b * DD + d) * LL + m0 + tx];
        float g = zv / (1.f + __expf(-zv));
        yg[((size_t)b * DD + d) * LL + m0 + tx] = ((v - mu) * r * wn[d] + bn[d]) * g;
    }
}

// ---------------- out_proj + residual (channel-major) ----------------
__global__ void out_proj_kernel(const float* __restrict__ yg, const float* __restrict__ wproj,
                                const float* __restrict__ x, float* __restrict__ out) {
    __shared__ float wt[32][DD];
    int l = blockIdx.x * 64 + threadIdx.x;
    int b = blockIdx.z;
    int c0 = blockIdx.y * 32;
    int t = threadIdx.y * 64 + threadIdx.x;
    for (int i = t; i < 32 * DD; i += 256)
        wt[i / DD][i % DD] = wproj[(size_t)(c0 + i / DD) * DD + (i % DD)];
    __syncthreads();
    const float* yb = yg + (size_t)b * DD * LL + l;
    float acc[8];
#pragma unroll
    for (int i = 0; i < 8; i++) acc[i] = 0.f;
    int cl0 = threadIdx.y * 8;
    for (int d = 0; d < DD; d++) {
        float yv = yb[(size_t)d * LL];
#pragma unroll
        for (int i = 0; i < 8; i++) acc[i] = fmaf(wt[cl0 + i][d], yv, acc[i]);
    }
#pragma unroll
    for (int i = 0; i < 8; i++) {
        int c = c0 + cl0 + i;
        size_t o = ((size_t)b * CC + c) * LL + l;
        out[o] = acc[i] + x[o];
    }
}

extern "C" void kernel_launch(void* const* d_in, const int* in_sizes, int n_in,
                              void* d_out, int out_size, void* d_ws, size_t ws_size,
                              hipStream_t stream) {
    const float* x          = (const float*)d_in[0];
    const float* ln_w       = (const float*)d_in[1];
    const float* ln_b       = (const float*)d_in[2];
    const float* in_proj_w  = (const float*)d_in[3];
    const float* conv_w     = (const float*)d_in[4];
    const float* conv_b     = (const float*)d_in[5];
    const float* x_proj_w   = (const float*)d_in[6];
    const float* dt_proj_w  = (const float*)d_in[7];
    const float* dt_proj_b  = (const float*)d_in[8];
    const float* A_log      = (const float*)d_in[9];
    const float* Ds         = (const float*)d_in[10];
    const float* out_norm_w = (const float*)d_in[11];
    const float* out_norm_b = (const float*)d_in[12];
    const float* out_proj_w = (const float*)d_in[13];
    float* out = (float*)d_out;

    const size_t P = (size_t)BB * CC * LL;  // 6,291,456 elements
    float* ws = (float*)d_ws;
    float* slot0 = ws;
    float* slot1 = ws + P;
    float* slot2 = ws + 2 * P;
    float* slot3 = ws + 3 * P;

    // lifetimes:
    //  slot0: xn -> xcv_cm (conv out, channel-major) -> ymT (pixel-major merge)
    //  slot1: xc (in_proj stream out) -> xdbl (2.62M) + cs (1.57M) + hinit (0.79M)
    //  slot2: z (kept until lngate)
    //  slot3: xcvT (pixel-major) -> ygate (channel-major)
    float* xn     = slot0;
    float* xc     = slot1;
    float* z      = slot2;
    float* xcv_cm = slot0;
    float* xcvT   = slot3;
    float* xdbl   = slot1;
    float* cs     = slot1 + (size_t)BB * KK * LL * 20;              // 2,621,440
    float* hinit  = cs + (size_t)BB * KK * CH * 8 * DD;             // +1,572,864
    float* ymT    = slot0;
    float* ygate  = slot3;

    // 1. LayerNorm
    ln_cf_kernel<<<(BB * LL) / 256, 256, 0, stream>>>(x, ln_w, ln_b, xn);
    // 2. in_proj -> xc (slot1), z (slot2)
    in_proj_kernel<<<dim3(LL / 64, (2 * DD) / 32, BB), dim3(64, 4), 0, stream>>>(
        xn, in_proj_w, xc, z);
    // 3. depthwise conv + SiLU -> xcv_cm (slot0, xn dead)
    dwconv_silu_kernel<<<(BB * DD * LL) / 256, 256, 0, stream>>>(xc, conv_w, conv_b, xcv_cm);
    // 4. transpose -> xcvT (slot3)
    transpose_kernel<<<dim3(LL / 64, DD / 64, BB), dim3(64, 4), 0, stream>>>(xcv_cm, xcvT);
    // 5. x_proj -> xdbl interleaved (slot1; xc dead)
    xproj_kernel<<<BB * (LL / 64), dim3(64, 4), 0, stream>>>(xcvT, x_proj_w, xdbl);
    // 6. zero merged-y accumulator (slot0; xcv_cm dead)
    hipMemsetAsync(ymT, 0, P * sizeof(float), stream);
    // 7. chunked scan
    scan_part1<<<BB * KK * CH, DD, 0, stream>>>(xcvT, xdbl, dt_proj_w, dt_proj_b, A_log, cs);
    scan_part2<<<(BB * KK * DD + 255) / 256, 256, 0, stream>>>(cs, hinit);
    scan_part3<<<BB * KK * CH, DD, 0, stream>>>(xcvT, xdbl, dt_proj_w, dt_proj_b, A_log, Ds,
                                                hinit, ymT);
    // 8. LN over D + silu(z) gate -> ygate channel-major (slot3; xcvT dead)
    lngate_kernel<<<BB * (LL / 64), dim3(64, 4), 0, stream>>>(ymT, z, out_norm_w, out_norm_b,
                                                              ygate);
    // 9. out_proj + residual
    out_proj_kernel<<<dim3(LL / 64, CC / 32, BB), dim3(64, 4), 0, stream>>>(
        ygate, out_proj_w, x, out);
}

// Round 4
// 493.002 us; speedup vs baseline: 11.1817x; 1.2645x over previous
//
#include <hip/hip_runtime.h>
#include <math.h>

#define BB 8
#define CC 192
#define HH 64
#define WW 64
#define LL 4096   // HH*WW
#define DD 192
#define NN 4
#define RR 12
#define KK 4
#define CH 32     // chunks per direction
#define SS 128    // chunk length (CH*SS == LL)

typedef __attribute__((ext_vector_type(8))) short short8;
typedef __attribute__((ext_vector_type(4))) float float4v;

__device__ inline ushort f2bf(float f) {
    union { float f; unsigned u; } v; v.f = f;
    unsigned r = v.u + 0x7FFFu + ((v.u >> 16) & 1u);
    return (ushort)(r >> 16);
}

// ---------------- LayerNorm (channels-first stats) -> pixel-major bf16 ----------------
// block (64,4); grid B*(LL/64). Reads x channel-major coalesced, writes (b,l,c) bf16.
__global__ void ln_pm_kernel(const float* __restrict__ x, const float* __restrict__ w,
                             const float* __restrict__ bias, ushort* __restrict__ xnT16) {
    __shared__ float xt[64 * 193];   // 49.4 KB
    __shared__ float red[2][4][64];
    __shared__ float stat[2][64];
    __shared__ float wls[CC], bls[CC];
    int b = blockIdx.x / (LL / 64);
    int m0 = (blockIdx.x % (LL / 64)) * 64;
    int tx = threadIdx.x, ty = threadIdx.y;
    int t = ty * 64 + tx;
    if (t < CC) { wls[t] = w[t]; bls[t] = bias[t]; }
    float s = 0.f, s2 = 0.f;
    for (int j = 0; j < 48; j++) {
        int c = ty * 48 + j;
        float v = x[((size_t)b * CC + c) * LL + m0 + tx];
        xt[tx * 193 + c] = v;
        s += v; s2 += v * v;
    }
    red[0][ty][tx] = s; red[1][ty][tx] = s2;
    __syncthreads();
    if (ty == 0) {
        float ss = red[0][0][tx] + red[0][1][tx] + red[0][2][tx] + red[0][3][tx];
        float ss2 = red[1][0][tx] + red[1][1][tx] + red[1][2][tx] + red[1][3][tx];
        float mu = ss / CC;
        float var = ss2 / CC - mu * mu;
        stat[0][tx] = mu;
        stat[1][tx] = rsqrtf(var + 1e-5f);
    }
    __syncthreads();
    for (int i = t; i < 64 * CC; i += 256) {
        int p = i / CC, c = i % CC;
        float v = (xt[p * 193 + c] - stat[0][p]) * stat[1][p] * wls[c] + bls[c];
        xnT16[((size_t)b * LL + m0 + p) * CC + c] = f2bf(v);
    }
}

// ---------------- in_proj MFMA: C[m=dd][n=l] = W(384x192) . xnT16^T ----------------
// grid (LL/128, 384/128, BB), block 256 (4 waves, 2x2), per-wave 64x64 via 4x4 MFMA tiles
__global__ __launch_bounds__(256) void in_proj_mfma(
        const ushort* __restrict__ xnT16, const float* __restrict__ wproj,
        float* __restrict__ xc, float* __restrict__ z) {
    __shared__ ushort At[128 * 40];  // 10.2 KB, row stride 40 bf16 (80 B)
    __shared__ ushort Bt[128 * 40];
    int b = blockIdx.z;
    int m0 = blockIdx.y * 128, n0 = blockIdx.x * 128;
    int tid = threadIdx.x;
    int wid = tid >> 6, lane = tid & 63;
    int wm = (wid & 1) * 64, wn = (wid >> 1) * 64;
    int lr = lane & 15, lq = lane >> 4;

    float4v acc[4][4] = {};

    for (int k0 = 0; k0 < CC; k0 += 32) {
        // stage A (weights fp32 -> bf16): 128 rows x 32 k
#pragma unroll
        for (int j = 0; j < 4; j++) {
            int i = tid + j * 256;           // 0..1023
            int row = i >> 3, seg = i & 7;   // seg*4 floats
            float4v v = *(const float4v*)(wproj + (size_t)(m0 + row) * CC + k0 + seg * 4);
            ushort* dst = &At[row * 40 + seg * 4];
            dst[0] = f2bf(v.x); dst[1] = f2bf(v.y); dst[2] = f2bf(v.z); dst[3] = f2bf(v.w);
        }
        // stage B (bf16): 128 rows x 32 k, 16B per lane
#pragma unroll
        for (int j = 0; j < 2; j++) {
            int i = tid + j * 256;           // 0..511
            int row = i >> 2, seg = i & 3;   // seg*8 bf16
            *(short8*)&Bt[row * 40 + seg * 8] =
                *(const short8*)(xnT16 + ((size_t)b * LL + n0 + row) * CC + k0 + seg * 8);
        }
        __syncthreads();
        short8 af[4], bf_[4];
#pragma unroll
        for (int mt = 0; mt < 4; mt++) af[mt] = *(short8*)&At[(wm + mt * 16 + lr) * 40 + lq * 8];
#pragma unroll
        for (int nt = 0; nt < 4; nt++) bf_[nt] = *(short8*)&Bt[(wn + nt * 16 + lr) * 40 + lq * 8];
#pragma unroll
        for (int mt = 0; mt < 4; mt++)
#pragma unroll
            for (int nt = 0; nt < 4; nt++)
                acc[mt][nt] = __builtin_amdgcn_mfma_f32_16x16x32_bf16(
                    af[mt], bf_[nt], acc[mt][nt], 0, 0, 0);
        __syncthreads();
    }
#pragma unroll
    for (int mt = 0; mt < 4; mt++)
#pragma unroll
        for (int nt = 0; nt < 4; nt++)
#pragma unroll
            for (int reg = 0; reg < 4; reg++) {
                int m = m0 + wm + mt * 16 + lq * 4 + reg;
                int n = n0 + wn + nt * 16 + lr;
                float v = acc[mt][nt][reg];
                if (m < DD) xc[((size_t)b * DD + m) * LL + n] = v;
                else        z[((size_t)b * DD + (m - DD)) * LL + n] = v;
            }
}

// ---------------- depthwise 3x3 conv + SiLU, channel-major in -> pixel-major out ----
// grid (HH, DD/64, BB), block (64,4)
__global__ void dwconv_t_kernel(const float* __restrict__ xc, const float* __restrict__ cw,
                                const float* __restrict__ cb, float* __restrict__ xcvT) {
    __shared__ float xin[64 * 198];  // [d][r][w+1], 3*66 = 198 per d; 50.7 KB
    int h = blockIdx.x;
    int d0 = blockIdx.y * 64;
    int b = blockIdx.z;
    int tx = threadIdx.x, ty = threadIdx.y;
    int tid = ty * 64 + tx;
    // zero the w-pads
    for (int j = tid; j < 64 * 6; j += 256) {
        int d = j / 6, rr = j % 6, r = rr >> 1, side = rr & 1;
        xin[d * 198 + r * 66 + (side ? 65 : 0)] = 0.f;
    }
    // load 3 rows x 64 d x 64 w (coalesced)
    for (int i = tid; i < 64 * 192; i += 256) {
        int d = i / 192, rem = i % 192, r = rem / 64, w = rem % 64;
        int hh = h + r - 1;
        float v = (hh >= 0 && hh < HH)
                      ? xc[((size_t)b * DD + d0 + d) * LL + hh * WW + w] : 0.f;
        xin[d * 198 + r * 66 + w + 1] = v;
    }
    __syncthreads();
    float yv[16];
#pragma unroll
    for (int j = 0; j < 16; j++) {
        int d = ty * 16 + j;
        float acc = cb[d0 + d];
#pragma unroll
        for (int r = 0; r < 3; r++)
#pragma unroll
            for (int cc2 = 0; cc2 < 3; cc2++)
                acc = fmaf(cw[(d0 + d) * 9 + r * 3 + cc2], xin[d * 198 + r * 66 + tx + cc2], acc);
        yv[j] = acc / (1.f + __expf(-acc));
    }
    __syncthreads();
    float* outt = xin;  // reuse: [w][d] padded 65
#pragma unroll
    for (int j = 0; j < 16; j++) outt[tx * 65 + ty * 16 + j] = yv[j];
    __syncthreads();
    for (int i = tid; i < 64 * 64; i += 256) {
        int p = i >> 6, d = i & 63;
        xcvT[((size_t)b * LL + h * WW + p) * DD + d0 + d] = outt[p * 65 + d];
    }
}

// ---------------- x_proj: pixel-major input -> interleaved x_dbl (b,k,m,20) ----------------
__global__ void xproj_kernel(const float* __restrict__ xT, const float* __restrict__ xpw,
                             float* __restrict__ xdbl) {
    __shared__ float xt[64 * 193];  // 49.4 KB
    int b = blockIdx.x / (LL / 64);
    int m0 = (blockIdx.x % (LL / 64)) * 64;
    int tx = threadIdx.x, k = threadIdx.y;
    int t = k * 64 + tx;
    const float* src = xT + ((size_t)b * LL + m0) * DD;
    for (int i = t; i < 64 * DD; i += 256) {
        int p = i / DD, d = i % DD;
        xt[p * 193 + d] = src[(size_t)p * DD + d];
    }
    __syncthreads();
    float acc[20];
#pragma unroll
    for (int c = 0; c < 20; c++) acc[c] = 0.f;
    const float* wk = xpw + (size_t)k * 20 * DD;
    for (int d = 0; d < DD; d++) {
        float xv = xt[tx * 193 + d];
#pragma unroll
        for (int c = 0; c < 20; c++) acc[c] = fmaf(wk[c * DD + d], xv, acc[c]);
    }
    float* o = xdbl + (((size_t)(b * KK + k) * LL) + m0 + tx) * 20;
#pragma unroll
    for (int c = 0; c < 20; c++) o[c] = acc[c];
}

// ---------------- scan part1: per-chunk local scan (h0 = 0) ----------------
__global__ void scan_part1(const float* __restrict__ uT, const float* __restrict__ xdbl,
                           const float* __restrict__ dtw, const float* __restrict__ dtb,
                           const float* __restrict__ A_log, float* __restrict__ cs) {
    int blk = blockIdx.x;
    int cch = blk % CH;
    int bk = blk / CH;
    int k = bk % KK, b = bk / KK;
    int d = threadIdx.x;

    float wrow[RR];
#pragma unroll
    for (int r = 0; r < RR; r++) wrow[r] = dtw[((size_t)k * DD + d) * RR + r];
    float bias = dtb[k * DD + d];
    float Av[NN];
#pragma unroll
    for (int n = 0; n < NN; n++) Av[n] = -__expf(A_log[((size_t)k * DD + d) * NN + n]);

    float Ap[NN] = {1.f, 1.f, 1.f, 1.f};
    float h[NN] = {0.f, 0.f, 0.f, 0.f};
    for (int t = 0; t < SS; t++) {
        int g = cch * SS + t;
        int base = (k & 2) ? (LL - 1 - g) : g;
        int m = (k & 1) ? ((base & 63) * 64 + (base >> 6)) : base;
        const float* xd = xdbl + ((size_t)bk * LL + m) * 20;
        float acc = bias;
#pragma unroll
        for (int r = 0; r < RR; r++) acc = fmaf(wrow[r], xd[r], acc);
        float e = __expf(acc);
        float dt = (acc > 20.f) ? acc : __logf(1.f + e);
        float u = uT[((size_t)b * LL + m) * DD + d];
        float dtu = dt * u;
#pragma unroll
        for (int n = 0; n < NN; n++) {
            float a = __expf(dt * Av[n]);
            Ap[n] *= a;
            h[n] = fmaf(a, h[n], dtu * xd[12 + n]);
        }
    }
    size_t cb = (size_t)bk * CH + cch;
#pragma unroll
    for (int n = 0; n < NN; n++) {
        cs[(cb * 8 + n) * DD + d] = Ap[n];
        cs[(cb * 8 + 4 + n) * DD + d] = h[n];
    }
}

// ---------------- scan part2 ----------------
__global__ void scan_part2(const float* __restrict__ cs, float* __restrict__ hinit) {
    int idx = blockIdx.x * blockDim.x + threadIdx.x;
    if (idx >= BB * KK * DD) return;
    int d = idx % DD;
    int bk = idx / DD;
    float h[NN] = {0.f, 0.f, 0.f, 0.f};
    for (int c = 0; c < CH; c++) {
        size_t cb = (size_t)bk * CH + c;
#pragma unroll
        for (int n = 0; n < NN; n++) hinit[(cb * 4 + n) * DD + d] = h[n];
#pragma unroll
        for (int n = 0; n < NN; n++)
            h[n] = fmaf(cs[(cb * 8 + n) * DD + d], h[n], cs[(cb * 8 + 4 + n) * DD + d]);
    }
}

// ---------------- scan part3 ----------------
__global__ void scan_part3(const float* __restrict__ uT, const float* __restrict__ xdbl,
                           const float* __restrict__ dtw, const float* __restrict__ dtb,
                           const float* __restrict__ A_log, const float* __restrict__ Ds,
                           const float* __restrict__ hinit, float* __restrict__ ymT) {
    int blk = blockIdx.x;
    int cch = blk % CH;
    int bk = blk / CH;
    int k = bk % KK, b = bk / KK;
    int d = threadIdx.x;

    float wrow[RR];
#pragma unroll
    for (int r = 0; r < RR; r++) wrow[r] = dtw[((size_t)k * DD + d) * RR + r];
    float bias = dtb[k * DD + d];
    float Av[NN];
#pragma unroll
    for (int n = 0; n < NN; n++) Av[n] = -__expf(A_log[((size_t)k * DD + d) * NN + n]);
    float Dval = Ds[k * DD + d];

    float h[NN];
    size_t cb = (size_t)bk * CH + cch;
#pragma unroll
    for (int n = 0; n < NN; n++) h[n] = hinit[(cb * 4 + n) * DD + d];

    for (int t = 0; t < SS; t++) {
        int g = cch * SS + t;
        int base = (k & 2) ? (LL - 1 - g) : g;
        int m = (k & 1) ? ((base & 63) * 64 + (base >> 6)) : base;
        const float* xd = xdbl + ((size_t)bk * LL + m) * 20;
        float acc = bias;
#pragma unroll
        for (int r = 0; r < RR; r++) acc = fmaf(wrow[r], xd[r], acc);
        float e = __expf(acc);
        float dt = (acc > 20.f) ? acc : __logf(1.f + e);
        float u = uT[((size_t)b * LL + m) * DD + d];
        float dtu = dt * u;
        float y = Dval * u;
#pragma unroll
        for (int n = 0; n < NN; n++) {
            float a = __expf(dt * Av[n]);
            h[n] = fmaf(a, h[n], dtu * xd[12 + n]);
            y = fmaf(h[n], xd[16 + n], y);
        }
        atomicAdd(&ymT[((size_t)b * LL + m) * DD + d], y);
    }
}

// ---------------- merge-LN over D + silu(z) gate -> pixel-major bf16 yg16 ----------------
__global__ void lngate_kernel(const float* __restrict__ ymT, const float* __restrict__ z,
                              const float* __restrict__ wn, const float* __restrict__ bn,
                              ushort* __restrict__ yg16) {
    __shared__ float yt[64 * 193];   // 49.4 KB
    __shared__ float red[2][4][64];
    __shared__ float stat[2][64];
    int b = blockIdx.x / (LL / 64);
    int m0 = (blockIdx.x % (LL / 64)) * 64;
    int tx = threadIdx.x, ty = threadIdx.y;
    int t = ty * 64 + tx;
    const float* src = ymT + ((size_t)b * LL + m0) * DD;
    for (int i = t; i < 64 * DD; i += 256) {
        int p = i / DD, d = i % DD;
        yt[p * 193 + d] = src[(size_t)p * DD + d];
    }
    __syncthreads();
    float s = 0.f, s2 = 0.f;
    for (int j = 0; j < 48; j++) {
        int d = ty * 48 + j;
        float v = yt[tx * 193 + d];
        s += v; s2 += v * v;
    }
    red[0][ty][tx] = s; red[1][ty][tx] = s2;
    __syncthreads();
    if (ty == 0) {
        float ss = red[0][0][tx] + red[0][1][tx] + red[0][2][tx] + red[0][3][tx];
        float ss2 = red[1][0][tx] + red[1][1][tx] + red[1][2][tx] + red[1][3][tx];
        float mu = ss / DD;
        float var = ss2 / DD - mu * mu;
        stat[0][tx] = mu;
        stat[1][tx] = rsqrtf(var + 1e-5f);
    }
    __syncthreads();
    float mu = stat[0][tx], r = stat[1][tx];
    for (int j = 0; j < 48; j++) {
        int d = ty * 48 + j;
        float v = yt[tx * 193 + d];
        float zv = z[((size_t)b * DD + d) * LL + m0 + tx];
        float g = zv / (1.f + __expf(-zv));
        yt[tx * 193 + d] = ((v - mu) * r * wn[d] + bn[d]) * g;
    }
    __syncthreads();
    for (int i = t; i < 64 * DD; i += 256) {
        int p = i / DD, d = i % DD;
        yg16[((size_t)b * LL + m0 + p) * DD + d] = f2bf(yt[p * 193 + d]);
    }
}

// ---------------- out_proj MFMA + residual: out = W_out(192x192) . yg16^T + x ----------
// grid (LL/128, 2, BB): second m-block covers rows 128..191 (partial)
__global__ __launch_bounds__(256) void out_proj_mfma(
        const ushort* __restrict__ yg16, const float* __restrict__ wproj,
        const float* __restrict__ x, float* __restrict__ out) {
    __shared__ ushort At[128 * 40];
    __shared__ ushort Bt[128 * 40];
    int b = blockIdx.z;
    int m0 = blockIdx.y * 128, n0 = blockIdx.x * 128;
    int tid = threadIdx.x;
    int wid = tid >> 6, lane = tid & 63;
    int wm = (wid & 1) * 64, wn = (wid >> 1) * 64;
    int lr = lane & 15, lq = lane >> 4;

    float4v acc[4][4] = {};

    for (int k0 = 0; k0 < DD; k0 += 32) {
#pragma unroll
        for (int j = 0; j < 4; j++) {
            int i = tid + j * 256;
            int row = i >> 3, seg = i & 7;
            ushort* dst = &At[row * 40 + seg * 4];
            if (m0 + row < CC) {
                float4v v = *(const float4v*)(wproj + (size_t)(m0 + row) * DD + k0 + seg * 4);
                dst[0] = f2bf(v.x); dst[1] = f2bf(v.y); dst[2] = f2bf(v.z); dst[3] = f2bf(v.w);
            } else {
                dst[0] = 0; dst[1] = 0; dst[2] = 0; dst[3] = 0;
            }
        }
#pragma unroll
        for (int j = 0; j < 2; j++) {
            int i = tid + j * 256;
            int row = i >> 2, seg = i & 3;
            *(short8*)&Bt[row * 40 + seg * 8] =
                *(const short8*)(yg16 + ((size_t)b * LL + n0 + row) * DD + k0 + seg * 8);
        }
        __syncthreads();
        short8 af[4], bf_[4];
#pragma unroll
        for (int mt = 0; mt < 4; mt++) af[mt] = *(short8*)&At[(wm + mt * 16 + lr) * 40 + lq * 8];
#pragma unroll
        for (int nt = 0; nt < 4; nt++) bf_[nt] = *(short8*)&Bt[(wn + nt * 16 + lr) * 40 + lq * 8];
#pragma unroll
        for (int mt = 0; mt < 4; mt++)
#pragma unroll
            for (int nt = 0; nt < 4; nt++)
                acc[mt][nt] = __builtin_amdgcn_mfma_f32_16x16x32_bf16(
                    af[mt], bf_[nt], acc[mt][nt], 0, 0, 0);
        __syncthreads();
    }
#pragma unroll
    for (int mt = 0; mt < 4; mt++)
#pragma unroll
        for (int nt = 0; nt < 4; nt++)
#pragma unroll
            for (int reg = 0; reg < 4; reg++) {
                int m = m0 + wm + mt * 16 + lq * 4 + reg;
                int n = n0 + wn + nt * 16 + lr;
                if (m < CC) {
                    size_t o = ((size_t)b * CC + m) * LL + n;
                    out[o] = acc[mt][nt][reg] + x[o];
                }
            }
}

extern "C" void kernel_launch(void* const* d_in, const int* in_sizes, int n_in,
                              void* d_out, int out_size, void* d_ws, size_t ws_size,
                              hipStream_t stream) {
    const float* x          = (const float*)d_in[0];
    const float* ln_w       = (const float*)d_in[1];
    const float* ln_b       = (const float*)d_in[2];
    const float* in_proj_w  = (const float*)d_in[3];
    const float* conv_w     = (const float*)d_in[4];
    const float* conv_b     = (const float*)d_in[5];
    const float* x_proj_w   = (const float*)d_in[6];
    const float* dt_proj_w  = (const float*)d_in[7];
    const float* dt_proj_b  = (const float*)d_in[8];
    const float* A_log      = (const float*)d_in[9];
    const float* Ds         = (const float*)d_in[10];
    const float* out_norm_w = (const float*)d_in[11];
    const float* out_norm_b = (const float*)d_in[12];
    const float* out_proj_w = (const float*)d_in[13];
    float* out = (float*)d_out;

    const size_t P = (size_t)BB * CC * LL;  // 6,291,456 elements
    float* ws = (float*)d_ws;
    float* slot0 = ws;
    float* slot1 = ws + P;
    float* slot2 = ws + 2 * P;
    float* slot3 = ws + 3 * P;

    // lifetimes:
    //  slot0: xnT16 (bf16, P/2 fl space) -> ymT (P)
    //  slot1: xc (P) -> xdbl(2.62M)+cs(1.57M)+hinit(0.79M) -> yg16 over xdbl region
    //  slot2: z (P)
    //  slot3: xcvT (P)
    ushort* xnT16 = (ushort*)slot0;
    float* xc     = slot1;
    float* z      = slot2;
    float* xcvT   = slot3;
    float* xdbl   = slot1;
    float* cs     = slot1 + (size_t)BB * KK * LL * 20;   // +2,621,440
    float* hinit  = cs + (size_t)BB * KK * CH * 8 * DD;  // +1,572,864
    float* ymT    = slot0;
    ushort* yg16  = (ushort*)slot1;

    // 1. LN -> pixel-major bf16
    ln_pm_kernel<<<BB * (LL / 64), dim3(64, 4), 0, stream>>>(x, ln_w, ln_b, xnT16);
    // 2. in_proj (MFMA) -> xc, z (channel-major fp32)
    in_proj_mfma<<<dim3(LL / 128, 3, BB), 256, 0, stream>>>(xnT16, in_proj_w, xc, z);
    // 3. depthwise conv + SiLU -> pixel-major xcvT
    dwconv_t_kernel<<<dim3(HH, DD / 64, BB), dim3(64, 4), 0, stream>>>(xc, conv_w, conv_b, xcvT);
    // 4. x_proj -> interleaved xdbl (xc dead)
    xproj_kernel<<<BB * (LL / 64), dim3(64, 4), 0, stream>>>(xcvT, x_proj_w, xdbl);
    // 5. zero merged-y accumulator (xnT16 dead)
    hipMemsetAsync(ymT, 0, P * sizeof(float), stream);
    // 6. chunked scan
    scan_part1<<<BB * KK * CH, DD, 0, stream>>>(xcvT, xdbl, dt_proj_w, dt_proj_b, A_log, cs);
    scan_part2<<<(BB * KK * DD + 255) / 256, 256, 0, stream>>>(cs, hinit);
    scan_part3<<<BB * KK * CH, DD, 0, stream>>>(xcvT, xdbl, dt_proj_w, dt_proj_b, A_log, Ds,
                                                hinit, ymT);
    // 7. LN over D + silu(z) gate -> pixel-major bf16 yg16 (xdbl dead)
    lngate_kernel<<<BB * (LL / 64), dim3(64, 4), 0, stream>>>(ymT, z, out_norm_w, out_norm_b,
                                                              yg16);
    // 8. out_proj (MFMA) + residual
    out_proj_mfma<<<dim3(LL / 128, 2, BB), 256, 0, stream>>>(yg16, out_proj_w, x, out);
}

// Round 5
// 396.569 us; speedup vs baseline: 13.9007x; 1.2432x over previous
//
#include <hip/hip_runtime.h>
#include <math.h>

#define BB 8
#define CC 192
#define HH 64
#define WW 64
#define LL 4096   // HH*WW
#define DD 192
#define NN 4
#define RR 12
#define KK 4
#define CH 32     // chunks per direction
#define SS 128    // chunk length (CH*SS == LL)

typedef __attribute__((ext_vector_type(8))) short short8;
typedef __attribute__((ext_vector_type(4))) float float4v;

__device__ inline ushort f2bf(float f) {
    union { float f; unsigned u; } v; v.f = f;
    unsigned r = v.u + 0x7FFFu + ((v.u >> 16) & 1u);
    return (ushort)(r >> 16);
}

// ---------------- LayerNorm (channels-first stats) -> pixel-major bf16 ----------------
__global__ void ln_pm_kernel(const float* __restrict__ x, const float* __restrict__ w,
                             const float* __restrict__ bias, ushort* __restrict__ xnT16) {
    __shared__ float xt[64 * 193];   // 49.4 KB
    __shared__ float red[2][4][64];
    __shared__ float stat[2][64];
    __shared__ float wls[CC], bls[CC];
    int b = blockIdx.x / (LL / 64);
    int m0 = (blockIdx.x % (LL / 64)) * 64;
    int tx = threadIdx.x, ty = threadIdx.y;
    int t = ty * 64 + tx;
    if (t < CC) { wls[t] = w[t]; bls[t] = bias[t]; }
    float s = 0.f, s2 = 0.f;
    for (int j = 0; j < 48; j++) {
        int c = ty * 48 + j;
        float v = x[((size_t)b * CC + c) * LL + m0 + tx];
        xt[tx * 193 + c] = v;
        s += v; s2 += v * v;
    }
    red[0][ty][tx] = s; red[1][ty][tx] = s2;
    __syncthreads();
    if (ty == 0) {
        float ss = red[0][0][tx] + red[0][1][tx] + red[0][2][tx] + red[0][3][tx];
        float ss2 = red[1][0][tx] + red[1][1][tx] + red[1][2][tx] + red[1][3][tx];
        float mu = ss / CC;
        float var = ss2 / CC - mu * mu;
        stat[0][tx] = mu;
        stat[1][tx] = rsqrtf(var + 1e-5f);
    }
    __syncthreads();
    for (int i = t; i < 64 * CC; i += 256) {
        int p = i / CC, c = i % CC;
        float v = (xt[p * 193 + c] - stat[0][p]) * stat[1][p] * wls[c] + bls[c];
        xnT16[((size_t)b * LL + m0 + p) * CC + c] = f2bf(v);
    }
}

// ---------------- in_proj MFMA ----------------
__global__ __launch_bounds__(256) void in_proj_mfma(
        const ushort* __restrict__ xnT16, const float* __restrict__ wproj,
        float* __restrict__ xc, float* __restrict__ z) {
    __shared__ ushort At[128 * 40];
    __shared__ ushort Bt[128 * 40];
    int b = blockIdx.z;
    int m0 = blockIdx.y * 128, n0 = blockIdx.x * 128;
    int tid = threadIdx.x;
    int wid = tid >> 6, lane = tid & 63;
    int wm = (wid & 1) * 64, wn = (wid >> 1) * 64;
    int lr = lane & 15, lq = lane >> 4;

    float4v acc[4][4] = {};

    for (int k0 = 0; k0 < CC; k0 += 32) {
#pragma unroll
        for (int j = 0; j < 4; j++) {
            int i = tid + j * 256;
            int row = i >> 3, seg = i & 7;
            float4v v = *(const float4v*)(wproj + (size_t)(m0 + row) * CC + k0 + seg * 4);
            ushort* dst = &At[row * 40 + seg * 4];
            dst[0] = f2bf(v.x); dst[1] = f2bf(v.y); dst[2] = f2bf(v.z); dst[3] = f2bf(v.w);
        }
#pragma unroll
        for (int j = 0; j < 2; j++) {
            int i = tid + j * 256;
            int row = i >> 2, seg = i & 3;
            *(short8*)&Bt[row * 40 + seg * 8] =
                *(const short8*)(xnT16 + ((size_t)b * LL + n0 + row) * CC + k0 + seg * 8);
        }
        __syncthreads();
        short8 af[4], bf_[4];
#pragma unroll
        for (int mt = 0; mt < 4; mt++) af[mt] = *(short8*)&At[(wm + mt * 16 + lr) * 40 + lq * 8];
#pragma unroll
        for (int nt = 0; nt < 4; nt++) bf_[nt] = *(short8*)&Bt[(wn + nt * 16 + lr) * 40 + lq * 8];
#pragma unroll
        for (int mt = 0; mt < 4; mt++)
#pragma unroll
            for (int nt = 0; nt < 4; nt++)
                acc[mt][nt] = __builtin_amdgcn_mfma_f32_16x16x32_bf16(
                    af[mt], bf_[nt], acc[mt][nt], 0, 0, 0);
        __syncthreads();
    }
#pragma unroll
    for (int mt = 0; mt < 4; mt++)
#pragma unroll
        for (int nt = 0; nt < 4; nt++)
#pragma unroll
            for (int reg = 0; reg < 4; reg++) {
                int m = m0 + wm + mt * 16 + lq * 4 + reg;
                int n = n0 + wn + nt * 16 + lr;
                float v = acc[mt][nt][reg];
                if (m < DD) xc[((size_t)b * DD + m) * LL + n] = v;
                else        z[((size_t)b * DD + (m - DD)) * LL + n] = v;
            }
}

// ---------------- depthwise 3x3 conv + SiLU, channel-major in -> pixel-major out ----
__global__ void dwconv_t_kernel(const float* __restrict__ xc, const float* __restrict__ cw,
                                const float* __restrict__ cb, float* __restrict__ xcvT) {
    __shared__ float xin[64 * 198];  // 50.7 KB
    int h = blockIdx.x;
    int d0 = blockIdx.y * 64;
    int b = blockIdx.z;
    int tx = threadIdx.x, ty = threadIdx.y;
    int tid = ty * 64 + tx;
    for (int j = tid; j < 64 * 6; j += 256) {
        int d = j / 6, rr = j % 6, r = rr >> 1, side = rr & 1;
        xin[d * 198 + r * 66 + (side ? 65 : 0)] = 0.f;
    }
    for (int i = tid; i < 64 * 192; i += 256) {
        int d = i / 192, rem = i % 192, r = rem / 64, w = rem % 64;
        int hh = h + r - 1;
        float v = (hh >= 0 && hh < HH)
                      ? xc[((size_t)b * DD + d0 + d) * LL + hh * WW + w] : 0.f;
        xin[d * 198 + r * 66 + w + 1] = v;
    }
    __syncthreads();
    float yv[16];
#pragma unroll
    for (int j = 0; j < 16; j++) {
        int d = ty * 16 + j;
        float acc = cb[d0 + d];
#pragma unroll
        for (int r = 0; r < 3; r++)
#pragma unroll
            for (int cc2 = 0; cc2 < 3; cc2++)
                acc = fmaf(cw[(d0 + d) * 9 + r * 3 + cc2], xin[d * 198 + r * 66 + tx + cc2], acc);
        yv[j] = acc / (1.f + __expf(-acc));
    }
    __syncthreads();
    float* outt = xin;
#pragma unroll
    for (int j = 0; j < 16; j++) outt[tx * 65 + ty * 16 + j] = yv[j];
    __syncthreads();
    for (int i = tid; i < 64 * 64; i += 256) {
        int p = i >> 6, d = i & 63;
        xcvT[((size_t)b * LL + h * WW + p) * DD + d0 + d] = outt[p * 65 + d];
    }
}

// ---------------- x_proj MFMA: xdbl(b,k,m,20) = W(80x192) . xcvT^T ----------------
// grid = (B*L)/128 blocks; block 256 (4 waves); wave: M=80 (5 tiles) x N=32 (2 tiles)
__global__ __launch_bounds__(256) void xproj_mfma(
        const float* __restrict__ xcvT, const float* __restrict__ xpw,
        float* __restrict__ xdbl) {
    __shared__ ushort At[80 * 200];  // 32.0 KB, stride 200 bf16
    __shared__ ushort Bt[128 * 40];  // 10.2 KB
    int tid = threadIdx.x;
    int wid = tid >> 6, lane = tid & 63;
    int lr = lane & 15, lq = lane >> 4;
    int wn = wid * 32;
    int p0 = blockIdx.x * 128;          // global pixel base
    int b = p0 >> 12;                   // p0 / LL (128 | LL so no b-crossing)
    int m0 = p0 & (LL - 1);

    // stage all weights (80 x 192) fp32 -> bf16, once
    for (int i = tid; i < 80 * 48; i += 256) {   // 48 float4s per row
        int row = i / 48, col = (i % 48) * 4;
        float4v v = *(const float4v*)(xpw + (size_t)row * DD + col);
        ushort* dst = &At[row * 200 + col];
        dst[0] = f2bf(v.x); dst[1] = f2bf(v.y); dst[2] = f2bf(v.z); dst[3] = f2bf(v.w);
    }

    float4v acc[5][2] = {};

    for (int k0 = 0; k0 < DD; k0 += 32) {
        // stage B: 128 pixels x 32 k, fp32 -> bf16
#pragma unroll
        for (int j = 0; j < 4; j++) {
            int i = tid + j * 256;           // 0..1023
            int row = i >> 3, seg = i & 7;
            float4v v = *(const float4v*)(xcvT + ((size_t)b * LL + m0 + row) * DD + k0 + seg * 4);
            ushort* dst = &Bt[row * 40 + seg * 4];
            dst[0] = f2bf(v.x); dst[1] = f2bf(v.y); dst[2] = f2bf(v.z); dst[3] = f2bf(v.w);
        }
        __syncthreads();
        short8 af[5], bf_[2];
#pragma unroll
        for (int mt = 0; mt < 5; mt++)
            af[mt] = *(short8*)&At[(mt * 16 + lr) * 200 + k0 + lq * 8];
#pragma unroll
        for (int nt = 0; nt < 2; nt++)
            bf_[nt] = *(short8*)&Bt[(wn + nt * 16 + lr) * 40 + lq * 8];
#pragma unroll
        for (int mt = 0; mt < 5; mt++)
#pragma unroll
            for (int nt = 0; nt < 2; nt++)
                acc[mt][nt] = __builtin_amdgcn_mfma_f32_16x16x32_bf16(
                    af[mt], bf_[nt], acc[mt][nt], 0, 0, 0);
        __syncthreads();
    }
    // epilogue: row = c-channel in [0,80) = k*20+c; 4-row groups never cross k (20 % 4 == 0)
#pragma unroll
    for (int mt = 0; mt < 5; mt++)
#pragma unroll
        for (int nt = 0; nt < 2; nt++) {
            int row0 = mt * 16 + lq * 4;
            int k = row0 / 20, c0 = row0 % 20;
            int m = m0 + wn + nt * 16 + lr;
            *(float4v*)(xdbl + (((size_t)(b * KK + k) * LL) + m) * 20 + c0) = acc[mt][nt];
        }
}

// ---------------- scan part1: per-chunk local scan (h0 = 0) ----------------
__global__ void scan_part1(const float* __restrict__ uT, const float* __restrict__ xdbl,
                           const float* __restrict__ dtw, const float* __restrict__ dtb,
                           const float* __restrict__ A_log, float* __restrict__ cs) {
    int blk = blockIdx.x;
    int cch = blk % CH;
    int bk = blk / CH;
    int k = bk % KK, b = bk / KK;
    int d = threadIdx.x;

    float wrow[RR];
#pragma unroll
    for (int r = 0; r < RR; r++) wrow[r] = dtw[((size_t)k * DD + d) * RR + r];
    float bias = dtb[k * DD + d];
    float Av[NN];
#pragma unroll
    for (int n = 0; n < NN; n++) Av[n] = -__expf(A_log[((size_t)k * DD + d) * NN + n]);

    float Ap[NN] = {1.f, 1.f, 1.f, 1.f};
    float h[NN] = {0.f, 0.f, 0.f, 0.f};
    for (int t = 0; t < SS; t++) {
        int g = cch * SS + t;
        int base = (k & 2) ? (LL - 1 - g) : g;
        int m = (k & 1) ? ((base & 63) * 64 + (base >> 6)) : base;
        const float* xd = xdbl + ((size_t)bk * LL + m) * 20;
        float acc = bias;
#pragma unroll
        for (int r = 0; r < RR; r++) acc = fmaf(wrow[r], xd[r], acc);
        float e = __expf(acc);
        float dt = (acc > 20.f) ? acc : __logf(1.f + e);
        float u = uT[((size_t)b * LL + m) * DD + d];
        float dtu = dt * u;
#pragma unroll
        for (int n = 0; n < NN; n++) {
            float a = __expf(dt * Av[n]);
            Ap[n] *= a;
            h[n] = fmaf(a, h[n], dtu * xd[12 + n]);
        }
    }
    size_t cb = (size_t)bk * CH + cch;
#pragma unroll
    for (int n = 0; n < NN; n++) {
        cs[(cb * 8 + n) * DD + d] = Ap[n];
        cs[(cb * 8 + 4 + n) * DD + d] = h[n];
    }
}

// ---------------- scan part2 ----------------
__global__ void scan_part2(const float* __restrict__ cs, float* __restrict__ hinit) {
    int idx = blockIdx.x * blockDim.x + threadIdx.x;
    if (idx >= BB * KK * DD) return;
    int d = idx % DD;
    int bk = idx / DD;
    float h[NN] = {0.f, 0.f, 0.f, 0.f};
    for (int c = 0; c < CH; c++) {
        size_t cb = (size_t)bk * CH + c;
#pragma unroll
        for (int n = 0; n < NN; n++) hinit[(cb * 4 + n) * DD + d] = h[n];
#pragma unroll
        for (int n = 0; n < NN; n++)
            h[n] = fmaf(cs[(cb * 8 + n) * DD + d], h[n], cs[(cb * 8 + 4 + n) * DD + d]);
    }
}

// ---------------- scan part3 ----------------
__global__ void scan_part3(const float* __restrict__ uT, const float* __restrict__ xdbl,
                           const float* __restrict__ dtw, const float* __restrict__ dtb,
                           const float* __restrict__ A_log, const float* __restrict__ Ds,
                           const float* __restrict__ hinit, float* __restrict__ ymT) {
    int blk = blockIdx.x;
    int cch = blk % CH;
    int bk = blk / CH;
    int k = bk % KK, b = bk / KK;
    int d = threadIdx.x;

    float wrow[RR];
#pragma unroll
    for (int r = 0; r < RR; r++) wrow[r] = dtw[((size_t)k * DD + d) * RR + r];
    float bias = dtb[k * DD + d];
    float Av[NN];
#pragma unroll
    for (int n = 0; n < NN; n++) Av[n] = -__expf(A_log[((size_t)k * DD + d) * NN + n]);
    float Dval = Ds[k * DD + d];

    float h[NN];
    size_t cb = (size_t)bk * CH + cch;
#pragma unroll
    for (int n = 0; n < NN; n++) h[n] = hinit[(cb * 4 + n) * DD + d];

    for (int t = 0; t < SS; t++) {
        int g = cch * SS + t;
        int base = (k & 2) ? (LL - 1 - g) : g;
        int m = (k & 1) ? ((base & 63) * 64 + (base >> 6)) : base;
        const float* xd = xdbl + ((size_t)bk * LL + m) * 20;
        float acc = bias;
#pragma unroll
        for (int r = 0; r < RR; r++) acc = fmaf(wrow[r], xd[r], acc);
        float e = __expf(acc);
        float dt = (acc > 20.f) ? acc : __logf(1.f + e);
        float u = uT[((size_t)b * LL + m) * DD + d];
        float dtu = dt * u;
        float y = Dval * u;
#pragma unroll
        for (int n = 0; n < NN; n++) {
            float a = __expf(dt * Av[n]);
            h[n] = fmaf(a, h[n], dtu * xd[12 + n]);
            y = fmaf(h[n], xd[16 + n], y);
        }
        atomicAdd(&ymT[((size_t)b * LL + m) * DD + d], y);
    }
}

// ---------------- merge-LN over D + silu(z) gate -> pixel-major bf16 yg16 ----------------
__global__ void lngate_kernel(const float* __restrict__ ymT, const float* __restrict__ z,
                              const float* __restrict__ wn, const float* __restrict__ bn,
                              ushort* __restrict__ yg16) {
    __shared__ float yt[64 * 193];
    __shared__ float red[2][4][64];
    __shared__ float stat[2][64];
    int b = blockIdx.x / (LL / 64);
    int m0 = (blockIdx.x % (LL / 64)) * 64;
    int tx = threadIdx.x, ty = threadIdx.y;
    int t = ty * 64 + tx;
    const float* src = ymT + ((size_t)b * LL + m0) * DD;
    for (int i = t; i < 64 * DD; i += 256) {
        int p = i / DD, d = i % DD;
        yt[p * 193 + d] = src[(size_t)p * DD + d];
    }
    __syncthreads();
    float s = 0.f, s2 = 0.f;
    for (int j = 0; j < 48; j++) {
        int d = ty * 48 + j;
        float v = yt[tx * 193 + d];
        s += v; s2 += v * v;
    }
    red[0][ty][tx] = s; red[1][ty][tx] = s2;
    __syncthreads();
    if (ty == 0) {
        float ss = red[0][0][tx] + red[0][1][tx] + red[0][2][tx] + red[0][3][tx];
        float ss2 = red[1][0][tx] + red[1][1][tx] + red[1][2][tx] + red[1][3][tx];
        float mu = ss / DD;
        float var = ss2 / DD - mu * mu;
        stat[0][tx] = mu;
        stat[1][tx] = rsqrtf(var + 1e-5f);
    }
    __syncthreads();
    float mu = stat[0][tx], r = stat[1][tx];
    for (int j = 0; j < 48; j++) {
        int d = ty * 48 + j;
        float v = yt[tx * 193 + d];
        float zv = z[((size_t)b * DD + d) * LL + m0 + tx];
        float g = zv / (1.f + __expf(-zv));
        yt[tx * 193 + d] = ((v - mu) * r * wn[d] + bn[d]) * g;
    }
    __syncthreads();
    for (int i = t; i < 64 * DD; i += 256) {
        int p = i / DD, d = i % DD;
        yg16[((size_t)b * LL + m0 + p) * DD + d] = f2bf(yt[p * 193 + d]);
    }
}

// ---------------- out_proj MFMA + residual ----------------
__global__ __launch_bounds__(256) void out_proj_mfma(
        const ushort* __restrict__ yg16, const float* __restrict__ wproj,
        const float* __restrict__ x, float* __restrict__ out) {
    __shared__ ushort At[128 * 40];
    __shared__ ushort Bt[128 * 40];
    int b = blockIdx.z;
    int m0 = blockIdx.y * 128, n0 = blockIdx.x * 128;
    int tid = threadIdx.x;
    int wid = tid >> 6, lane = tid & 63;
    int wm = (wid & 1) * 64, wn = (wid >> 1) * 64;
    int lr = lane & 15, lq = lane >> 4;

    float4v acc[4][4] = {};

    for (int k0 = 0; k0 < DD; k0 += 32) {
#pragma unroll
        for (int j = 0; j < 4; j++) {
            int i = tid + j * 256;
            int row = i >> 3, seg = i & 7;
            ushort* dst = &At[row * 40 + seg * 4];
            if (m0 + row < CC) {
                float4v v = *(const float4v*)(wproj + (size_t)(m0 + row) * DD + k0 + seg * 4);
                dst[0] = f2bf(v.x); dst[1] = f2bf(v.y); dst[2] = f2bf(v.z); dst[3] = f2bf(v.w);
            } else {
                dst[0] = 0; dst[1] = 0; dst[2] = 0; dst[3] = 0;
            }
        }
#pragma unroll
        for (int j = 0; j < 2; j++) {
            int i = tid + j * 256;
            int row = i >> 2, seg = i & 3;
            *(short8*)&Bt[row * 40 + seg * 8] =
                *(const short8*)(yg16 + ((size_t)b * LL + n0 + row) * DD + k0 + seg * 8);
        }
        __syncthreads();
        short8 af[4], bf_[4];
#pragma unroll
        for (int mt = 0; mt < 4; mt++) af[mt] = *(short8*)&At[(wm + mt * 16 + lr) * 40 + lq * 8];
#pragma unroll
        for (int nt = 0; nt < 4; nt++) bf_[nt] = *(short8*)&Bt[(wn + nt * 16 + lr) * 40 + lq * 8];
#pragma unroll
        for (int mt = 0; mt < 4; mt++)
#pragma unroll
            for (int nt = 0; nt < 4; nt++)
                acc[mt][nt] = __builtin_amdgcn_mfma_f32_16x16x32_bf16(
                    af[mt], bf_[nt], acc[mt][nt], 0, 0, 0);
        __syncthreads();
    }
#pragma unroll
    for (int mt = 0; mt < 4; mt++)
#pragma unroll
        for (int nt = 0; nt < 4; nt++)
#pragma unroll
            for (int reg = 0; reg < 4; reg++) {
                int m = m0 + wm + mt * 16 + lq * 4 + reg;
                int n = n0 + wn + nt * 16 + lr;
                if (m < CC) {
                    size_t o = ((size_t)b * CC + m) * LL + n;
                    out[o] = acc[mt][nt][reg] + x[o];
                }
            }
}

extern "C" void kernel_launch(void* const* d_in, const int* in_sizes, int n_in,
                              void* d_out, int out_size, void* d_ws, size_t ws_size,
                              hipStream_t stream) {
    const float* x          = (const float*)d_in[0];
    const float* ln_w       = (const float*)d_in[1];
    const float* ln_b       = (const float*)d_in[2];
    const float* in_proj_w  = (const float*)d_in[3];
    const float* conv_w     = (const float*)d_in[4];
    const float* conv_b     = (const float*)d_in[5];
    const float* x_proj_w   = (const float*)d_in[6];
    const float* dt_proj_w  = (const float*)d_in[7];
    const float* dt_proj_b  = (const float*)d_in[8];
    const float* A_log      = (const float*)d_in[9];
    const float* Ds         = (const float*)d_in[10];
    const float* out_norm_w = (const float*)d_in[11];
    const float* out_norm_b = (const float*)d_in[12];
    const float* out_proj_w = (const float*)d_in[13];
    float* out = (float*)d_out;

    const size_t P = (size_t)BB * CC * LL;  // 6,291,456 elements
    float* ws = (float*)d_ws;
    float* slot0 = ws;
    float* slot1 = ws + P;
    float* slot2 = ws + 2 * P;
    float* slot3 = ws + 3 * P;

    ushort* xnT16 = (ushort*)slot0;
    float* xc     = slot1;
    float* z      = slot2;
    float* xcvT   = slot3;
    float* xdbl   = slot1;
    float* cs     = slot1 + (size_t)BB * KK * LL * 20;   // +2,621,440
    float* hinit  = cs + (size_t)BB * KK * CH * 8 * DD;  // +1,572,864
    float* ymT    = slot0;
    ushort* yg16  = (ushort*)slot1;

    // 1. LN -> pixel-major bf16
    ln_pm_kernel<<<BB * (LL / 64), dim3(64, 4), 0, stream>>>(x, ln_w, ln_b, xnT16);
    // 2. in_proj (MFMA) -> xc, z (channel-major fp32)
    in_proj_mfma<<<dim3(LL / 128, 3, BB), 256, 0, stream>>>(xnT16, in_proj_w, xc, z);
    // 3. depthwise conv + SiLU -> pixel-major xcvT
    dwconv_t_kernel<<<dim3(HH, DD / 64, BB), dim3(64, 4), 0, stream>>>(xc, conv_w, conv_b, xcvT);
    // 4. x_proj (MFMA) -> interleaved xdbl (xc dead)
    xproj_mfma<<<(BB * LL) / 128, 256, 0, stream>>>(xcvT, x_proj_w, xdbl);
    // 5. zero merged-y accumulator (xnT16 dead)
    hipMemsetAsync(ymT, 0, P * sizeof(float), stream);
    // 6. chunked scan
    scan_part1<<<BB * KK * CH, DD, 0, stream>>>(xcvT, xdbl, dt_proj_w, dt_proj_b, A_log, cs);
    scan_part2<<<(BB * KK * DD + 255) / 256, 256, 0, stream>>>(cs, hinit);
    scan_part3<<<BB * KK * CH, DD, 0, stream>>>(xcvT, xdbl, dt_proj_w, dt_proj_b, A_log, Ds,
                                                hinit, ymT);
    // 7. LN over D + silu(z) gate -> pixel-major bf16 yg16 (xdbl dead)
    lngate_kernel<<<BB * (LL / 64), dim3(64, 4), 0, stream>>>(ymT, z, out_norm_w, out_norm_b,
                                                              yg16);
    // 8. out_proj (MFMA) + residual
    out_proj_mfma<<<dim3(LL / 128, 2, BB), 256, 0, stream>>>(yg16, out_proj_w, x, out);
}

// Round 6
// 388.277 us; speedup vs baseline: 14.1976x; 1.0214x over previous
//
#include <hip/hip_runtime.h>
#include <math.h>

#define BB 8
#define CC 192
#define HH 64
#define WW 64
#define LL 4096   // HH*WW
#define DD 192
#define NN 4
#define RR 12
#define KK 4
#define CH 64     // chunks per direction
#define SS 64     // chunk length (CH*SS == LL)

typedef __attribute__((ext_vector_type(8))) short short8;
typedef __attribute__((ext_vector_type(4))) float float4v;

__device__ inline ushort f2bf(float f) {
    union { float f; unsigned u; } v; v.f = f;
    unsigned r = v.u + 0x7FFFu + ((v.u >> 16) & 1u);
    return (ushort)(r >> 16);
}
__device__ inline float bf2f(ushort u) {
    union { unsigned u; float f; } v; v.u = ((unsigned)u) << 16; return v.f;
}

// ---------------- LayerNorm (channels-first stats) -> pixel-major bf16 ----------------
__global__ void ln_pm_kernel(const float* __restrict__ x, const float* __restrict__ w,
                             const float* __restrict__ bias, ushort* __restrict__ xnT16) {
    __shared__ float xt[64 * 193];   // 49.4 KB
    __shared__ float red[2][4][64];
    __shared__ float stat[2][64];
    __shared__ float wls[CC], bls[CC];
    int b = blockIdx.x / (LL / 64);
    int m0 = (blockIdx.x % (LL / 64)) * 64;
    int tx = threadIdx.x, ty = threadIdx.y;
    int t = ty * 64 + tx;
    if (t < CC) { wls[t] = w[t]; bls[t] = bias[t]; }
    float s = 0.f, s2 = 0.f;
    for (int j = 0; j < 48; j++) {
        int c = ty * 48 + j;
        float v = x[((size_t)b * CC + c) * LL + m0 + tx];
        xt[tx * 193 + c] = v;
        s += v; s2 += v * v;
    }
    red[0][ty][tx] = s; red[1][ty][tx] = s2;
    __syncthreads();
    if (ty == 0) {
        float ss = red[0][0][tx] + red[0][1][tx] + red[0][2][tx] + red[0][3][tx];
        float ss2 = red[1][0][tx] + red[1][1][tx] + red[1][2][tx] + red[1][3][tx];
        float mu = ss / CC;
        float var = ss2 / CC - mu * mu;
        stat[0][tx] = mu;
        stat[1][tx] = rsqrtf(var + 1e-5f);
    }
    __syncthreads();
    for (int i = t; i < 64 * CC; i += 256) {
        int p = i / CC, c = i % CC;
        float v = (xt[p * 193 + c] - stat[0][p]) * stat[1][p] * wls[c] + bls[c];
        xnT16[((size_t)b * LL + m0 + p) * CC + c] = f2bf(v);
    }
}

// ---------------- in_proj MFMA ----------------
__global__ __launch_bounds__(256) void in_proj_mfma(
        const ushort* __restrict__ xnT16, const float* __restrict__ wproj,
        float* __restrict__ xc, float* __restrict__ z) {
    __shared__ ushort At[128 * 40];
    __shared__ ushort Bt[128 * 40];
    int b = blockIdx.z;
    int m0 = blockIdx.y * 128, n0 = blockIdx.x * 128;
    int tid = threadIdx.x;
    int wid = tid >> 6, lane = tid & 63;
    int wm = (wid & 1) * 64, wn = (wid >> 1) * 64;
    int lr = lane & 15, lq = lane >> 4;

    float4v acc[4][4] = {};

    for (int k0 = 0; k0 < CC; k0 += 32) {
#pragma unroll
        for (int j = 0; j < 4; j++) {
            int i = tid + j * 256;
            int row = i >> 3, seg = i & 7;
            float4v v = *(const float4v*)(wproj + (size_t)(m0 + row) * CC + k0 + seg * 4);
            ushort* dst = &At[row * 40 + seg * 4];
            dst[0] = f2bf(v.x); dst[1] = f2bf(v.y); dst[2] = f2bf(v.z); dst[3] = f2bf(v.w);
        }
#pragma unroll
        for (int j = 0; j < 2; j++) {
            int i = tid + j * 256;
            int row = i >> 2, seg = i & 3;
            *(short8*)&Bt[row * 40 + seg * 8] =
                *(const short8*)(xnT16 + ((size_t)b * LL + n0 + row) * CC + k0 + seg * 8);
        }
        __syncthreads();
        short8 af[4], bf_[4];
#pragma unroll
        for (int mt = 0; mt < 4; mt++) af[mt] = *(short8*)&At[(wm + mt * 16 + lr) * 40 + lq * 8];
#pragma unroll
        for (int nt = 0; nt < 4; nt++) bf_[nt] = *(short8*)&Bt[(wn + nt * 16 + lr) * 40 + lq * 8];
#pragma unroll
        for (int mt = 0; mt < 4; mt++)
#pragma unroll
            for (int nt = 0; nt < 4; nt++)
                acc[mt][nt] = __builtin_amdgcn_mfma_f32_16x16x32_bf16(
                    af[mt], bf_[nt], acc[mt][nt], 0, 0, 0);
        __syncthreads();
    }
#pragma unroll
    for (int mt = 0; mt < 4; mt++)
#pragma unroll
        for (int nt = 0; nt < 4; nt++)
#pragma unroll
            for (int reg = 0; reg < 4; reg++) {
                int m = m0 + wm + mt * 16 + lq * 4 + reg;
                int n = n0 + wn + nt * 16 + lr;
                float v = acc[mt][nt][reg];
                if (m < DD) xc[((size_t)b * DD + m) * LL + n] = v;
                else        z[((size_t)b * DD + (m - DD)) * LL + n] = v;
            }
}

// ---------------- depthwise 3x3 conv + SiLU, channel-major in -> pixel-major bf16 out ----
__global__ void dwconv_t_kernel(const float* __restrict__ xc, const float* __restrict__ cw,
                                const float* __restrict__ cb, ushort* __restrict__ xcvT16) {
    __shared__ float xin[64 * 198];  // 50.7 KB
    int h = blockIdx.x;
    int d0 = blockIdx.y * 64;
    int b = blockIdx.z;
    int tx = threadIdx.x, ty = threadIdx.y;
    int tid = ty * 64 + tx;
    for (int j = tid; j < 64 * 6; j += 256) {
        int d = j / 6, rr = j % 6, r = rr >> 1, side = rr & 1;
        xin[d * 198 + r * 66 + (side ? 65 : 0)] = 0.f;
    }
    for (int i = tid; i < 64 * 192; i += 256) {
        int d = i / 192, rem = i % 192, r = rem / 64, w = rem % 64;
        int hh = h + r - 1;
        float v = (hh >= 0 && hh < HH)
                      ? xc[((size_t)b * DD + d0 + d) * LL + hh * WW + w] : 0.f;
        xin[d * 198 + r * 66 + w + 1] = v;
    }
    __syncthreads();
    float yv[16];
#pragma unroll
    for (int j = 0; j < 16; j++) {
        int d = ty * 16 + j;
        float acc = cb[d0 + d];
#pragma unroll
        for (int r = 0; r < 3; r++)
#pragma unroll
            for (int cc2 = 0; cc2 < 3; cc2++)
                acc = fmaf(cw[(d0 + d) * 9 + r * 3 + cc2], xin[d * 198 + r * 66 + tx + cc2], acc);
        yv[j] = acc / (1.f + __expf(-acc));
    }
    __syncthreads();
    float* outt = xin;
#pragma unroll
    for (int j = 0; j < 16; j++) outt[tx * 65 + ty * 16 + j] = yv[j];
    __syncthreads();
    for (int i = tid; i < 64 * 64; i += 256) {
        int p = i >> 6, d = i & 63;
        xcvT16[((size_t)b * LL + h * WW + p) * DD + d0 + d] = f2bf(outt[p * 65 + d]);
    }
}

// ---------------- x_proj MFMA: xdbl(b,k,m,20) = W(80x192) . xcvT16^T ----------------
__global__ __launch_bounds__(256) void xproj_mfma(
        const ushort* __restrict__ xT16, const float* __restrict__ xpw,
        float* __restrict__ xdbl) {
    __shared__ ushort At[80 * 200];  // 32.0 KB
    __shared__ ushort Bt[128 * 40];  // 10.2 KB
    int tid = threadIdx.x;
    int wid = tid >> 6, lane = tid & 63;
    int lr = lane & 15, lq = lane >> 4;
    int wn = wid * 32;
    int p0 = blockIdx.x * 128;
    int b = p0 >> 12;
    int m0 = p0 & (LL - 1);

    for (int i = tid; i < 80 * 48; i += 256) {
        int row = i / 48, col = (i % 48) * 4;
        float4v v = *(const float4v*)(xpw + (size_t)row * DD + col);
        ushort* dst = &At[row * 200 + col];
        dst[0] = f2bf(v.x); dst[1] = f2bf(v.y); dst[2] = f2bf(v.z); dst[3] = f2bf(v.w);
    }

    float4v acc[5][2] = {};

    for (int k0 = 0; k0 < DD; k0 += 32) {
#pragma unroll
        for (int j = 0; j < 2; j++) {
            int i = tid + j * 256;
            int row = i >> 2, seg = i & 3;
            *(short8*)&Bt[row * 40 + seg * 8] =
                *(const short8*)(xT16 + ((size_t)b * LL + m0 + row) * DD + k0 + seg * 8);
        }
        __syncthreads();
        short8 af[5], bf_[2];
#pragma unroll
        for (int mt = 0; mt < 5; mt++)
            af[mt] = *(short8*)&At[(mt * 16 + lr) * 200 + k0 + lq * 8];
#pragma unroll
        for (int nt = 0; nt < 2; nt++)
            bf_[nt] = *(short8*)&Bt[(wn + nt * 16 + lr) * 40 + lq * 8];
#pragma unroll
        for (int mt = 0; mt < 5; mt++)
#pragma unroll
            for (int nt = 0; nt < 2; nt++)
                acc[mt][nt] = __builtin_amdgcn_mfma_f32_16x16x32_bf16(
                    af[mt], bf_[nt], acc[mt][nt], 0, 0, 0);
        __syncthreads();
    }
#pragma unroll
    for (int mt = 0; mt < 5; mt++)
#pragma unroll
        for (int nt = 0; nt < 2; nt++) {
            int row0 = mt * 16 + lq * 4;
            int k = row0 / 20, c0 = row0 % 20;
            int m = m0 + wn + nt * 16 + lr;
            *(float4v*)(xdbl + (((size_t)(b * KK + k) * LL) + m) * 20 + c0) = acc[mt][nt];
        }
}

// ---------------- scan part1: per-chunk local scan (h0 = 0) ----------------
__global__ void scan_part1(const ushort* __restrict__ uT16, const float* __restrict__ xdbl,
                           const float* __restrict__ dtw, const float* __restrict__ dtb,
                           const float* __restrict__ A_log, float* __restrict__ cs) {
    int blk = blockIdx.x;
    int cch = blk % CH;
    int bk = blk / CH;
    int k = bk % KK, b = bk / KK;
    int d = threadIdx.x;

    float wrow[RR];
#pragma unroll
    for (int r = 0; r < RR; r++) wrow[r] = dtw[((size_t)k * DD + d) * RR + r];
    float bias = dtb[k * DD + d];
    float Av[NN];
#pragma unroll
    for (int n = 0; n < NN; n++) Av[n] = -__expf(A_log[((size_t)k * DD + d) * NN + n]);

    float Ap[NN] = {1.f, 1.f, 1.f, 1.f};
    float h[NN] = {0.f, 0.f, 0.f, 0.f};
    for (int t = 0; t < SS; t++) {
        int g = cch * SS + t;
        int base = (k & 2) ? (LL - 1 - g) : g;
        int m = (k & 1) ? ((base & 63) * 64 + (base >> 6)) : base;
        const float* xd = xdbl + ((size_t)bk * LL + m) * 20;
        float acc = bias;
#pragma unroll
        for (int r = 0; r < RR; r++) acc = fmaf(wrow[r], xd[r], acc);
        float e = __expf(acc);
        float dt = (acc > 20.f) ? acc : __logf(1.f + e);
        float u = bf2f(uT16[((size_t)b * LL + m) * DD + d]);
        float dtu = dt * u;
#pragma unroll
        for (int n = 0; n < NN; n++) {
            float a = __expf(dt * Av[n]);
            Ap[n] *= a;
            h[n] = fmaf(a, h[n], dtu * xd[12 + n]);
        }
    }
    size_t cb = (size_t)bk * CH + cch;
#pragma unroll
    for (int n = 0; n < NN; n++) {
        cs[(cb * 8 + n) * DD + d] = Ap[n];
        cs[(cb * 8 + 4 + n) * DD + d] = h[n];
    }
}

// ---------------- scan part2 ----------------
__global__ void scan_part2(const float* __restrict__ cs, float* __restrict__ hinit) {
    int idx = blockIdx.x * blockDim.x + threadIdx.x;
    if (idx >= BB * KK * DD) return;
    int d = idx % DD;
    int bk = idx / DD;
    float h[NN] = {0.f, 0.f, 0.f, 0.f};
    for (int c = 0; c < CH; c++) {
        size_t cb = (size_t)bk * CH + c;
#pragma unroll
        for (int n = 0; n < NN; n++) hinit[(cb * 4 + n) * DD + d] = h[n];
#pragma unroll
        for (int n = 0; n < NN; n++)
            h[n] = fmaf(cs[(cb * 8 + n) * DD + d], h[n], cs[(cb * 8 + 4 + n) * DD + d]);
    }
}

// ---------------- scan part3 ----------------
__global__ void scan_part3(const ushort* __restrict__ uT16, const float* __restrict__ xdbl,
                           const float* __restrict__ dtw, const float* __restrict__ dtb,
                           const float* __restrict__ A_log, const float* __restrict__ Ds,
                           const float* __restrict__ hinit, float* __restrict__ ymT) {
    int blk = blockIdx.x;
    int cch = blk % CH;
    int bk = blk / CH;
    int k = bk % KK, b = bk / KK;
    int d = threadIdx.x;

    float wrow[RR];
#pragma unroll
    for (int r = 0; r < RR; r++) wrow[r] = dtw[((size_t)k * DD + d) * RR + r];
    float bias = dtb[k * DD + d];
    float Av[NN];
#pragma unroll
    for (int n = 0; n < NN; n++) Av[n] = -__expf(A_log[((size_t)k * DD + d) * NN + n]);
    float Dval = Ds[k * DD + d];

    float h[NN];
    size_t cb = (size_t)bk * CH + cch;
#pragma unroll
    for (int n = 0; n < NN; n++) h[n] = hinit[(cb * 4 + n) * DD + d];

    for (int t = 0; t < SS; t++) {
        int g = cch * SS + t;
        int base = (k & 2) ? (LL - 1 - g) : g;
        int m = (k & 1) ? ((base & 63) * 64 + (base >> 6)) : base;
        const float* xd = xdbl + ((size_t)bk * LL + m) * 20;
        float acc = bias;
#pragma unroll
        for (int r = 0; r < RR; r++) acc = fmaf(wrow[r], xd[r], acc);
        float e = __expf(acc);
        float dt = (acc > 20.f) ? acc : __logf(1.f + e);
        float u = bf2f(uT16[((size_t)b * LL + m) * DD + d]);
        float dtu = dt * u;
        float y = Dval * u;
#pragma unroll
        for (int n = 0; n < NN; n++) {
            float a = __expf(dt * Av[n]);
            h[n] = fmaf(a, h[n], dtu * xd[12 + n]);
            y = fmaf(h[n], xd[16 + n], y);
        }
        atomicAdd(&ymT[((size_t)b * LL + m) * DD + d], y);
    }
}

// ---------------- merge-LN over D + silu(z) gate -> pixel-major bf16 yg16 ----------------
__global__ void lngate_kernel(const float* __restrict__ ymT, const float* __restrict__ z,
                              const float* __restrict__ wn, const float* __restrict__ bn,
                              ushort* __restrict__ yg16) {
    __shared__ float yt[64 * 193];
    __shared__ float red[2][4][64];
    __shared__ float stat[2][64];
    int b = blockIdx.x / (LL / 64);
    int m0 = (blockIdx.x % (LL / 64)) * 64;
    int tx = threadIdx.x, ty = threadIdx.y;
    int t = ty * 64 + tx;
    const float* src = ymT + ((size_t)b * LL + m0) * DD;
    for (int i = t; i < 64 * DD; i += 256) {
        int p = i / DD, d = i % DD;
        yt[p * 193 + d] = src[(size_t)p * DD + d];
    }
    __syncthreads();
    float s = 0.f, s2 = 0.f;
    for (int j = 0; j < 48; j++) {
        int d = ty * 48 + j;
        float v = yt[tx * 193 + d];
        s += v; s2 += v * v;
    }
    red[0][ty][tx] = s; red[1][ty][tx] = s2;
    __syncthreads();
    if (ty == 0) {
        float ss = red[0][0][tx] + red[0][1][tx] + red[0][2][tx] + red[0][3][tx];
        float ss2 = red[1][0][tx] + red[1][1][tx] + red[1][2][tx] + red[1][3][tx];
        float mu = ss / DD;
        float var = ss2 / DD - mu * mu;
        stat[0][tx] = mu;
        stat[1][tx] = rsqrtf(var + 1e-5f);
    }
    __syncthreads();
    float mu = stat[0][tx], r = stat[1][tx];
    for (int j = 0; j < 48; j++) {
        int d = ty * 48 + j;
        float v = yt[tx * 193 + d];
        float zv = z[((size_t)b * DD + d) * LL + m0 + tx];
        float g = zv / (1.f + __expf(-zv));
        yt[tx * 193 + d] = ((v - mu) * r * wn[d] + bn[d]) * g;
    }
    __syncthreads();
    for (int i = t; i < 64 * DD; i += 256) {
        int p = i / DD, d = i % DD;
        yg16[((size_t)b * LL + m0 + p) * DD + d] = f2bf(yt[p * 193 + d]);
    }
}

// ---------------- out_proj MFMA + residual ----------------
__global__ __launch_bounds__(256) void out_proj_mfma(
        const ushort* __restrict__ yg16, const float* __restrict__ wproj,
        const float* __restrict__ x, float* __restrict__ out) {
    __shared__ ushort At[128 * 40];
    __shared__ ushort Bt[128 * 40];
    int b = blockIdx.z;
    int m0 = blockIdx.y * 128, n0 = blockIdx.x * 128;
    int tid = threadIdx.x;
    int wid = tid >> 6, lane = tid & 63;
    int wm = (wid & 1) * 64, wn = (wid >> 1) * 64;
    int lr = lane & 15, lq = lane >> 4;

    float4v acc[4][4] = {};

    for (int k0 = 0; k0 < DD; k0 += 32) {
#pragma unroll
        for (int j = 0; j < 4; j++) {
            int i = tid + j * 256;
            int row = i >> 3, seg = i & 7;
            ushort* dst = &At[row * 40 + seg * 4];
            if (m0 + row < CC) {
                float4v v = *(const float4v*)(wproj + (size_t)(m0 + row) * DD + k0 + seg * 4);
                dst[0] = f2bf(v.x); dst[1] = f2bf(v.y); dst[2] = f2bf(v.z); dst[3] = f2bf(v.w);
            } else {
                dst[0] = 0; dst[1] = 0; dst[2] = 0; dst[3] = 0;
            }
        }
#pragma unroll
        for (int j = 0; j < 2; j++) {
            int i = tid + j * 256;
            int row = i >> 2, seg = i & 3;
            *(short8*)&Bt[row * 40 + seg * 8] =
                *(const short8*)(yg16 + ((size_t)b * LL + n0 + row) * DD + k0 + seg * 8);
        }
        __syncthreads();
        short8 af[4], bf_[4];
#pragma unroll
        for (int mt = 0; mt < 4; mt++) af[mt] = *(short8*)&At[(wm + mt * 16 + lr) * 40 + lq * 8];
#pragma unroll
        for (int nt = 0; nt < 4; nt++) bf_[nt] = *(short8*)&Bt[(wn + nt * 16 + lr) * 40 + lq * 8];
#pragma unroll
        for (int mt = 0; mt < 4; mt++)
#pragma unroll
            for (int nt = 0; nt < 4; nt++)
                acc[mt][nt] = __builtin_amdgcn_mfma_f32_16x16x32_bf16(
                    af[mt], bf_[nt], acc[mt][nt], 0, 0, 0);
        __syncthreads();
    }
#pragma unroll
    for (int mt = 0; mt < 4; mt++)
#pragma unroll
        for (int nt = 0; nt < 4; nt++)
#pragma unroll
            for (int reg = 0; reg < 4; reg++) {
                int m = m0 + wm + mt * 16 + lq * 4 + reg;
                int n = n0 + wn + nt * 16 + lr;
                if (m < CC) {
                    size_t o = ((size_t)b * CC + m) * LL + n;
                    out[o] = acc[mt][nt][reg] + x[o];
                }
            }
}

extern "C" void kernel_launch(void* const* d_in, const int* in_sizes, int n_in,
                              void* d_out, int out_size, void* d_ws, size_t ws_size,
                              hipStream_t stream) {
    const float* x          = (const float*)d_in[0];
    const float* ln_w       = (const float*)d_in[1];
    const float* ln_b       = (const float*)d_in[2];
    const float* in_proj_w  = (const float*)d_in[3];
    const float* conv_w     = (const float*)d_in[4];
    const float* conv_b     = (const float*)d_in[5];
    const float* x_proj_w   = (const float*)d_in[6];
    const float* dt_proj_w  = (const float*)d_in[7];
    const float* dt_proj_b  = (const float*)d_in[8];
    const float* A_log      = (const float*)d_in[9];
    const float* Ds         = (const float*)d_in[10];
    const float* out_norm_w = (const float*)d_in[11];
    const float* out_norm_b = (const float*)d_in[12];
    const float* out_proj_w = (const float*)d_in[13];
    float* out = (float*)d_out;

    const size_t P = (size_t)BB * CC * LL;  // 6,291,456 elements
    float* ws = (float*)d_ws;
    float* slot0 = ws;
    float* slot1 = ws + P;
    float* slot2 = ws + 2 * P;
    float* slot3 = ws + 3 * P;

    // lifetimes:
    //  slot0: xnT16 (P ushorts = P/2 floats) -> ymT (P floats)
    //  slot1: xc (P) -> xdbl (2.62M) + hinit (1.57M) -> yg16 over xdbl region
    //  slot2: z (P)
    //  slot3: xcvT16 (P ushorts = P/2 floats) + cs (P/2 floats = 3.14M, exactly B*K*CH*8*D)
    ushort* xnT16  = (ushort*)slot0;
    float* xc      = slot1;
    float* z       = slot2;
    ushort* xcvT16 = (ushort*)slot3;
    float* cs      = slot3 + P / 2;                      // B*K*CH*8*DD = 3,145,728 ✓
    float* xdbl    = slot1;
    float* hinit   = slot1 + (size_t)BB * KK * LL * 20;  // +2,621,440; size 1,572,864
    float* ymT     = slot0;
    ushort* yg16   = (ushort*)slot1;

    // 1. LN -> pixel-major bf16
    ln_pm_kernel<<<BB * (LL / 64), dim3(64, 4), 0, stream>>>(x, ln_w, ln_b, xnT16);
    // 2. in_proj (MFMA) -> xc, z (channel-major fp32)
    in_proj_mfma<<<dim3(LL / 128, 3, BB), 256, 0, stream>>>(xnT16, in_proj_w, xc, z);
    // 3. depthwise conv + SiLU -> pixel-major bf16 xcvT16
    dwconv_t_kernel<<<dim3(HH, DD / 64, BB), dim3(64, 4), 0, stream>>>(xc, conv_w, conv_b,
                                                                       xcvT16);
    // 4. x_proj (MFMA) -> interleaved xdbl (xc dead)
    xproj_mfma<<<(BB * LL) / 128, 256, 0, stream>>>(xcvT16, x_proj_w, xdbl);
    // 5. zero merged-y accumulator (xnT16 dead)
    hipMemsetAsync(ymT, 0, P * sizeof(float), stream);
    // 6. chunked scan (SS=64, CH=64: 2048 blocks per pass for latency hiding)
    scan_part1<<<BB * KK * CH, DD, 0, stream>>>(xcvT16, xdbl, dt_proj_w, dt_proj_b, A_log, cs);
    scan_part2<<<(BB * KK * DD + 255) / 256, 256, 0, stream>>>(cs, hinit);
    scan_part3<<<BB * KK * CH, DD, 0, stream>>>(xcvT16, xdbl, dt_proj_w, dt_proj_b, A_log, Ds,
                                                hinit, ymT);
    // 7. LN over D + silu(z) gate -> pixel-major bf16 yg16 (xdbl dead)
    lngate_kernel<<<BB * (LL / 64), dim3(64, 4), 0, stream>>>(ymT, z, out_norm_w, out_norm_b,
                                                              yg16);
    // 8. out_proj (MFMA) + residual
    out_proj_mfma<<<dim3(LL / 128, 2, BB), 256, 0, stream>>>(yg16, out_proj_w, x, out);
}